// Round 13
// baseline (206.230 us; speedup 1.0000x reference)
//
#include <hip/hip_runtime.h>
#include <hip/hip_bf16.h>

#define BB 8
#define SS 4096
#define DD 128
#define HH 8
#define NBUCK 64
#define CHUNKSZ 64
#define NCHUNK 512      // HH*SS/CHUNKSZ
#define HSTOT 32768     // HH*SS
#define ROWB 256        // bf16 tile row stride in bytes (T2 XOR swizzle, no pad)
#define SWZ(row, off) ((off) ^ (((row) & 7) << 4))

typedef __attribute__((ext_vector_type(8))) short short8_t;   // 8 bf16 = 4 VGPR
typedef __attribute__((ext_vector_type(4))) float f32x4;

static __device__ __forceinline__ unsigned short f2bf(float f) {
    __hip_bfloat16 h = __float2bfloat16(f);
    return *reinterpret_cast<unsigned short*>(&h);
}
static __device__ __forceinline__ unsigned int pk2bf(float lo, float hi) {
    __hip_bfloat162 h = __float22bfloat162_rn(make_float2(lo, hi));   // v_cvt_pk_bf16_f32
    return *reinterpret_cast<unsigned int*>(&h);
}
static __device__ __forceinline__ float bf2f(unsigned short u) {
    return __uint_as_float(((unsigned int)u) << 16);
}

// ---------------- Kernel A: LSH hashing (register-resident) ------------------
// R9 structure; R12 XCD batch pinning; R13: h==0 blocks also compute
// ninv_ws[b][t] = rsqrt(sum(qk[t]^2)+eps) nearly free (rows already in regs).
__global__ __launch_bounds__(256) void hash_kernel(
    const float* __restrict__ qk, const float* __restrict__ rot,
    unsigned char* __restrict__ bucket_ws, float* __restrict__ bucket_out,
    float* __restrict__ ninv_ws)
{
    const int tid = threadIdx.x;
    const int bid = blockIdx.x;            // 0..2047 = tile(5) | h(3) | b(3)
    const int b   = bid & 7;               // XCD-pinned batch
    const int h   = (bid >> 3) & 7;
    const int t0  = (bid >> 6) * 128;
    const int tg  = tid >> 3;              // token group 0..31 (4 tokens each)
    const int jq  = tid & 7;               // j-quad 0..7 (4 columns each)

    const float* qbase = qk + ((size_t)b * SS + t0 + tg * 4) * DD;
    const float* rbase = rot + h * 32 + jq * 4;   // rot[f][h][j], f-stride 256

    float acc[4][4];
    float ssq[4] = {0.f, 0.f, 0.f, 0.f};
    #pragma unroll
    for (int r = 0; r < 4; ++r)
        #pragma unroll
        for (int j = 0; j < 4; ++j) acc[r][j] = 0.f;

    for (int c = 0; c < 16; ++c) {         // f in chunks of 8
        float4 qv[4][2];
        #pragma unroll
        for (int r = 0; r < 4; ++r) {
            qv[r][0] = *reinterpret_cast<const float4*>(qbase + r * DD + c * 8);
            qv[r][1] = *reinterpret_cast<const float4*>(qbase + r * DD + c * 8 + 4);
        }
        if (h == 0) {                      // ninv side-product (1/8 of blocks)
            #pragma unroll
            for (int r = 0; r < 4; ++r) {
                float4 a0 = qv[r][0], a1 = qv[r][1];
                float s = ssq[r];
                s = fmaf(a0.x, a0.x, s); s = fmaf(a0.y, a0.y, s);
                s = fmaf(a0.z, a0.z, s); s = fmaf(a0.w, a0.w, s);
                s = fmaf(a1.x, a1.x, s); s = fmaf(a1.y, a1.y, s);
                s = fmaf(a1.z, a1.z, s); s = fmaf(a1.w, a1.w, s);
                ssq[r] = s;
            }
        }
        float4 rv[8];
        #pragma unroll
        for (int ff = 0; ff < 8; ++ff)
            rv[ff] = *reinterpret_cast<const float4*>(rbase + (size_t)(c * 8 + ff) * (HH * 32));
        #pragma unroll
        for (int ff = 0; ff < 8; ++ff) {
            #pragma unroll
            for (int r = 0; r < 4; ++r) {
                const float4 qh = qv[r][ff >> 2];
                const float qs = (ff & 2) ? ((ff & 1) ? qh.w : qh.z)
                                          : ((ff & 1) ? qh.y : qh.x);
                acc[r][0] = fmaf(qs, rv[ff].x, acc[r][0]);
                acc[r][1] = fmaf(qs, rv[ff].y, acc[r][1]);
                acc[r][2] = fmaf(qs, rv[ff].z, acc[r][2]);
                acc[r][3] = fmaf(qs, rv[ff].w, acc[r][3]);
            }
        }
    }

    if (h == 0 && jq == 0) {
        #pragma unroll
        for (int r = 0; r < 4; ++r)
            ninv_ws[(size_t)b * SS + t0 + tg * 4 + r] = rsqrtf(ssq[r] + 1e-6f);
    }

    const float TAU = 0.01f;
    #pragma unroll
    for (int r = 0; r < 4; ++r) {
        float bv = -3.0e38f; int bi = 0;
        #pragma unroll
        for (int j = 0; j < 4; ++j) {
            float v = acc[r][j];
            if (v > bv) { bv = v; bi = jq * 4 + j; }
        }
        #pragma unroll
        for (int j = 0; j < 4; ++j) {
            float v = -acc[r][j];
            if (v > bv) { bv = v; bi = 32 + jq * 4 + j; }
        }
        #pragma unroll
        for (int off = 1; off < 8; off <<= 1) {
            float ov = __shfl_xor(bv, off);
            int   oi = __shfl_xor(bi, off);
            if (ov > bv || (ov == bv && oi < bi)) { bv = ov; bi = oi; }
        }
        const float thrv = bv - TAU;
        int cnt = 0;
        #pragma unroll
        for (int j = 0; j < 4; ++j) {
            cnt += (acc[r][j]  > thrv) ? 1 : 0;
            cnt += (-acc[r][j] > thrv) ? 1 : 0;
        }
        #pragma unroll
        for (int off = 1; off < 8; off <<= 1) cnt += __shfl_xor(cnt, off);

        const int t = t0 + tg * 4 + r;
        if (cnt > 1) {
            const float* qrow = qk + ((size_t)b * SS + t) * DD;
            double bvd = -1.0e300; int bid2 = 64;
            #pragma unroll
            for (int j = 0; j < 4; ++j) {
                const bool fp = (acc[r][j] > thrv);
                const bool fn = (-acc[r][j] > thrv);
                if (fp || fn) {
                    const float* rcol = rot + h * 32 + jq * 4 + j;
                    double a = 0.0;
                    for (int f = 0; f < DD; ++f)
                        a = fma((double)qrow[f], (double)rcol[(size_t)f * (HH * 32)], a);
                    if (fp &&  a > bvd)                         { bvd = a;  bid2 = jq * 4 + j; }
                    if (fn && (-a > bvd ||
                               (-a == bvd && 32 + jq * 4 + j < bid2))) { bvd = -a; bid2 = 32 + jq * 4 + j; }
                }
            }
            #pragma unroll
            for (int off = 1; off < 8; off <<= 1) {
                double ov = __shfl_xor(bvd, off);
                int    oi = __shfl_xor(bid2, off);
                if (ov > bvd || (ov == bvd && oi < bid2)) { bvd = ov; bid2 = oi; }
            }
            bi = bid2;
        }
        if (jq == 0) {
            const size_t o = ((size_t)b * HH + h) * SS + t;
            bucket_ws[o]  = (unsigned char)bi;
            bucket_out[o] = (float)(bi + h * NBUCK);
        }
    }
}

// ---------------- Kernel B: stable counting sort per (b,h) -------------------
__global__ __launch_bounds__(256) void sort_kernel(
    const unsigned char* __restrict__ bucket_ws, int* __restrict__ st)
{
    __shared__ unsigned int hist[256 * 65];   // padded stride 65
    __shared__ unsigned int totals[64];
    const int tid = threadIdx.x;
    const int bh  = blockIdx.x;               // 0..63 = b*8+h

    unsigned int* hrow = &hist[tid * 65];
    #pragma unroll
    for (int j = 0; j < 65; ++j) hrow[j] = 0u;

    const uint4 raw = *reinterpret_cast<const uint4*>(bucket_ws + (size_t)bh * SS + tid * 16);
    unsigned int w[4] = {raw.x, raw.y, raw.z, raw.w};

    #pragma unroll
    for (int c = 0; c < 16; ++c) {
        unsigned int bk = (w[c >> 2] >> ((c & 3) * 8)) & 255u;
        hrow[bk] += 1u;
    }
    __syncthreads();

    if (tid < 64) {
        unsigned int run = 0;
        for (int c2 = 0; c2 < 256; ++c2) {
            unsigned int x = hist[c2 * 65 + tid];
            hist[c2 * 65 + tid] = run;
            run += x;
        }
        totals[tid] = run;
    }
    __syncthreads();
    if (tid == 0) {
        unsigned int base = 0;
        for (int k = 0; k < 64; ++k) { unsigned int x = totals[k]; totals[k] = base; base += x; }
    }
    __syncthreads();

    int* dst = st + (size_t)bh * SS;
    #pragma unroll
    for (int c = 0; c < 16; ++c) {
        unsigned int bk = (w[c >> 2] >> ((c & 3) * 8)) & 255u;
        unsigned int pos = totals[bk] + hrow[bk];
        hrow[bk] += 1u;
        dst[pos] = tid * 16 + c;
    }
}

// ---------------- Kernel C: chunked attention via bf16 MFMA ------------------
// R13: LDS = exactly 32768 B (K tile 128x256, T2 XOR swizzle) -> 5 blocks/CU.
// tks register-cached from global st[] (no LDS array); ninv from ninv_ws
// (computed by hash h==0 blocks). P[0,16K)+Vt[16K,32K) overlay K after QK^T.
__global__ __launch_bounds__(256, 5) void attn_kernel(
    const float* __restrict__ qk, const float* __restrict__ vv,
    const int* __restrict__ st, const float* __restrict__ ninv_ws,
    float* __restrict__ logits_ws, void* __restrict__ o_ws, const int obf16)
{
    __shared__ __align__(16) char smem[32768];
    char*  Kb = smem;
    char*  Pb = smem;                          // [0,16384) after Kb retired
    char*  Vt = smem + 16384;                  // [16384,32768) after Kb retired

    const int tid = threadIdx.x;
    const int bc  = blockIdx.x;
    const int b   = bc & 7;                    // XCD-pinned batch
    const int c   = bc >> 3;                   // chunk 0..511
    const int h   = c >> 6;
    const int cprev = (c == 0) ? (NCHUNK - 1) : (c - 1);
    const int* stb  = st + (size_t)b * HSTOT;

    // own K-row index straight from global (L2-hot)
    const int rowk  = tid >> 1, halfk = tid & 1;
    const int t_mine = stb[(size_t)((rowk < 64) ? c : cprev) * CHUNKSZ + (rowk & 63)];

    const int w  = tid >> 6;     // wave id: q-tile rows 16w..16w+15
    const int ln = tid & 63;
    const int cc = ln & 15;      // fragment col lane
    const int g  = ln >> 4;      // fragment k-group / row-group
    const int kp = tid & 63;     // V: token pair 2kp,2kp+1
    const int db = tid >> 6;     // V: dim sub-block

    // register caches (global reads, overlap the K staging)
    int tks_k[8]; float ninv_r[8];
    #pragma unroll
    for (int j = 0; j < 8; ++j) {
        const int idx = 16 * j + cc;
        const int tk  = stb[(size_t)((idx < 64) ? c : cprev) * CHUNKSZ + (idx & 63)];
        tks_k[j] = tk;
        ninv_r[j] = ninv_ws[(size_t)b * SS + tk];
    }
    int tq[4];
    #pragma unroll
    for (int jr = 0; jr < 4; ++jr)
        tq[jr] = stb[(size_t)c * CHUNKSZ + (16 * w + 4 * g + jr)];
    const int idxa = 2 * kp, idxb = 2 * kp + 1;
    const int tva = stb[(size_t)((idxa < 64) ? c : cprev) * CHUNKSZ + (idxa & 63)];
    const int tvb = stb[(size_t)((idxb < 64) ? c : cprev) * CHUNKSZ + (idxb & 63)];

    // ---- stage K (raw qk rows, bf16, swizzled) ------------------------------
    {
        const float* srow = qk + ((size_t)b * SS + t_mine) * DD + halfk * 64;
        char* krow = Kb + (size_t)rowk * ROWB;
        #pragma unroll
        for (int i = 0; i < 8; ++i) {
            float4 v0 = *reinterpret_cast<const float4*>(srow + i * 8);
            float4 v1 = *reinterpret_cast<const float4*>(srow + i * 8 + 4);
            uint4 pk;
            pk.x = pk2bf(v0.x, v0.y); pk.y = pk2bf(v0.z, v0.w);
            pk.z = pk2bf(v1.x, v1.y); pk.w = pk2bf(v1.z, v1.w);
            *reinterpret_cast<uint4*>(krow + SWZ(rowk, halfk * 128 + i * 16)) = pk;
        }
    }
    __syncthreads();

    // ---- QK^T ---------------------------------------------------------------
    short8_t aq[4];
    #pragma unroll
    for (int ks = 0; ks < 4; ++ks) {
        const int row = 16 * w + cc;
        aq[ks] = *reinterpret_cast<const short8_t*>(Kb + (size_t)row * ROWB + SWZ(row, ks * 64 + g * 16));
    }

    f32x4 acc[8];
    __builtin_amdgcn_s_setprio(1);
    #pragma unroll
    for (int j = 0; j < 8; ++j) {
        acc[j] = (f32x4){0.f, 0.f, 0.f, 0.f};
        #pragma unroll
        for (int ks = 0; ks < 4; ++ks) {
            const int row = 16 * j + cc;
            short8_t bk = *reinterpret_cast<const short8_t*>(Kb + (size_t)row * ROWB + SWZ(row, ks * 64 + g * 16));
            acc[j] = __builtin_amdgcn_mfma_f32_16x16x32_bf16(aq[ks], bk, acc[j], 0, 0, 0);
        }
    }
    __builtin_amdgcn_s_setprio(0);

    // ---- softmax (regs) -----------------------------------------------------
    const float SCALE = 0.088388347648318447f;   // 128^-0.5
    float lse[4];
    float pr[8][4];
    #pragma unroll
    for (int jr = 0; jr < 4; ++jr) {
        float m = -3.0e38f;
        #pragma unroll
        for (int j = 0; j < 8; ++j) {
            float val = acc[j][jr] * (ninv_r[j] * SCALE);
            if (tks_k[j] == tq[jr]) val = -1e5f;
            pr[j][jr] = val;
            m = fmaxf(m, val);
        }
        #pragma unroll
        for (int off = 1; off < 16; off <<= 1) m = fmaxf(m, __shfl_xor(m, off));
        float ssum = 0.f;
        #pragma unroll
        for (int j = 0; j < 8; ++j) { float ex = expf(pr[j][jr] - m); pr[j][jr] = ex; ssum += ex; }
        #pragma unroll
        for (int off = 1; off < 16; off <<= 1) ssum += __shfl_xor(ssum, off);
        const float inv = 1.0f / ssum;
        #pragma unroll
        for (int j = 0; j < 8; ++j) pr[j][jr] *= inv;
        lse[jr] = m + logf(ssum);
    }

    // ---- prefetch V phase 0 (dims 0..63) into regs --------------------------
    const float* vra = vv + ((size_t)b * SS + tva) * DD + db * 16;
    const float* vrb = vv + ((size_t)b * SS + tvb) * DD + db * 16;
    float4 va[4], vbr[4];
    #pragma unroll
    for (int i = 0; i < 4; ++i) {
        va[i]  = *reinterpret_cast<const float4*>(vra + i * 4);
        vbr[i] = *reinterpret_cast<const float4*>(vrb + i * 4);
    }

    __syncthreads();   // all Kb reads done; Pb/Vt may be written

    // ---- write P (bf16, swizzled) -------------------------------------------
    #pragma unroll
    for (int jr = 0; jr < 4; ++jr) {
        const int q = 16 * w + 4 * g + jr;
        #pragma unroll
        for (int j = 0; j < 8; ++j)
            *reinterpret_cast<unsigned short*>(Pb + (size_t)q * ROWB + SWZ(q, (16 * j + cc) * 2)) = f2bf(pr[j][jr]);
    }
    if (cc == 0) {
        #pragma unroll
        for (int jr = 0; jr < 4; ++jr)
            logits_ws[((size_t)b * HH + h) * SS + tq[jr]] = lse[jr];
    }
    // ---- write V phase 0 to Vt (swizzled) -----------------------------------
    {
        const float* fa = reinterpret_cast<const float*>(va);
        const float* fb = reinterpret_cast<const float*>(vbr);
        #pragma unroll
        for (int i = 0; i < 16; ++i) {
            const int dl = db * 16 + i;
            *reinterpret_cast<unsigned int*>(Vt + (size_t)dl * ROWB + SWZ(dl, kp * 4)) = pk2bf(fa[i], fb[i]);
        }
    }
    // ---- prefetch V phase 1 (dims 64..127) into regs (T14 split) ------------
    #pragma unroll
    for (int i = 0; i < 4; ++i) {
        va[i]  = *reinterpret_cast<const float4*>(vra + 64 + i * 4);
        vbr[i] = *reinterpret_cast<const float4*>(vrb + 64 + i * 4);
    }
    __syncthreads();   // Pb + Vt(phase 0) visible

    // ---- PV -----------------------------------------------------------------
    short8_t pa[4];
    #pragma unroll
    for (int ks = 0; ks < 4; ++ks) {
        const int row = 16 * w + cc;
        pa[ks] = *reinterpret_cast<const short8_t*>(Pb + (size_t)row * ROWB + SWZ(row, ks * 64 + g * 16));
    }

    f32x4 oacc[8];
    __builtin_amdgcn_s_setprio(1);
    #pragma unroll
    for (int dt = 0; dt < 4; ++dt) {       // phase A: output dims 0..63
        oacc[dt] = (f32x4){0.f, 0.f, 0.f, 0.f};
        #pragma unroll
        for (int ks = 0; ks < 4; ++ks) {
            const int row = 16 * dt + cc;
            short8_t vb = *reinterpret_cast<const short8_t*>(Vt + (size_t)row * ROWB + SWZ(row, ks * 64 + g * 16));
            oacc[dt] = __builtin_amdgcn_mfma_f32_16x16x32_bf16(pa[ks], vb, oacc[dt], 0, 0, 0);
        }
    }
    __builtin_amdgcn_s_setprio(0);
    __syncthreads();   // phase-A reads of Vt done

    // ---- write V phase 1 to Vt (swizzled) -----------------------------------
    {
        const float* fa = reinterpret_cast<const float*>(va);
        const float* fb = reinterpret_cast<const float*>(vbr);
        #pragma unroll
        for (int i = 0; i < 16; ++i) {
            const int dl = db * 16 + i;
            *reinterpret_cast<unsigned int*>(Vt + (size_t)dl * ROWB + SWZ(dl, kp * 4)) = pk2bf(fa[i], fb[i]);
        }
    }
    __syncthreads();

    __builtin_amdgcn_s_setprio(1);
    #pragma unroll
    for (int dt = 4; dt < 8; ++dt) {       // phase B: output dims 64..127
        oacc[dt] = (f32x4){0.f, 0.f, 0.f, 0.f};
        #pragma unroll
        for (int ks = 0; ks < 4; ++ks) {
            const int row = 16 * (dt - 4) + cc;
            short8_t vb = *reinterpret_cast<const short8_t*>(Vt + (size_t)row * ROWB + SWZ(row, ks * 64 + g * 16));
            oacc[dt] = __builtin_amdgcn_mfma_f32_16x16x32_bf16(pa[ks], vb, oacc[dt], 0, 0, 0);
        }
    }
    __builtin_amdgcn_s_setprio(0);

    // ---- scatter per-round outputs ------------------------------------------
    #pragma unroll
    for (int jr = 0; jr < 4; ++jr) {
        const int t = tq[jr];
        const size_t base = (((size_t)b * HH + h) * SS + t) * DD + cc;
        if (!obf16) {
            float* op = (float*)o_ws;
            #pragma unroll
            for (int dt = 0; dt < 8; ++dt) op[base + 16 * dt] = oacc[dt][jr];
        } else {
            unsigned short* op = (unsigned short*)o_ws;
            #pragma unroll
            for (int dt = 0; dt < 8; ++dt) op[base + 16 * dt] = f2bf(oacc[dt][jr]);
        }
    }
}

// ---------------- Kernel D: softmax-combine over hash rounds -----------------
__global__ __launch_bounds__(256) void combine_kernel(
    const float* __restrict__ logits_ws, const void* __restrict__ o_ws,
    float* __restrict__ outp, const int obf16)
{
    const int gid = blockIdx.x * 256 + threadIdx.x;
    const int row = gid >> 5;     // (b,t)
    const int seg = gid & 31;     // 4-float segment of D
    const int b = row >> 12;
    const int t = row & 4095;

    float l[8];
    float m = -3.0e38f;
    #pragma unroll
    for (int hh = 0; hh < 8; ++hh) {
        l[hh] = logits_ws[((size_t)b * HH + hh) * SS + t];
        m = fmaxf(m, l[hh]);
    }
    float ssum = 0.f;
    #pragma unroll
    for (int hh = 0; hh < 8; ++hh) { l[hh] = expf(l[hh] - m); ssum += l[hh]; }
    const float inv = 1.0f / ssum;

    float a0 = 0.f, a1 = 0.f, a2 = 0.f, a3 = 0.f;
    #pragma unroll
    for (int hh = 0; hh < 8; ++hh) {
        const float wgt = l[hh] * inv;
        const size_t base = (((size_t)b * HH + hh) * SS + t) * DD + seg * 4;
        if (!obf16) {
            float4 ov = *reinterpret_cast<const float4*>((const float*)o_ws + base);
            a0 = fmaf(wgt, ov.x, a0); a1 = fmaf(wgt, ov.y, a1);
            a2 = fmaf(wgt, ov.z, a2); a3 = fmaf(wgt, ov.w, a3);
        } else {
            uint2 u = *reinterpret_cast<const uint2*>((const unsigned short*)o_ws + base);
            a0 = fmaf(wgt, bf2f((unsigned short)(u.x & 0xffffu)), a0);
            a1 = fmaf(wgt, bf2f((unsigned short)(u.x >> 16)), a1);
            a2 = fmaf(wgt, bf2f((unsigned short)(u.y & 0xffffu)), a2);
            a3 = fmaf(wgt, bf2f((unsigned short)(u.y >> 16)), a3);
        }
    }
    *reinterpret_cast<float4*>(outp + ((size_t)b * SS + t) * DD + seg * 4) =
        make_float4(a0, a1, a2, a3);
}

extern "C" void kernel_launch(void* const* d_in, const int* in_sizes, int n_in,
                              void* d_out, int out_size, void* d_ws, size_t ws_size,
                              hipStream_t stream) {
    const float* qk  = (const float*)d_in[0];
    const float* v   = (const float*)d_in[1];
    const float* rot = (const float*)d_in[2];

    float* out        = (float*)d_out;
    float* bucket_out = out + (size_t)BB * SS * DD;   // buckets written as f32

    char* ws = (char*)d_ws;
    int*            st        = (int*)ws;                              // 1,048,576 B
    unsigned char*  bucket_ws = (unsigned char*)(ws + 1048576);        //   262,144 B
    float*          logits_ws = (float*)(ws + 1048576 + 262144);       // 1,048,576 B
    float*          ninv_ws   = (float*)(ws + 2359296);                //   131,072 B
    void*           o_ws      = (void*)(ws + 2490368);                 // big scratch

    const int obf16 = 1;   // bf16 o-scratch: halves attn WRITE + combine read traffic

    hipLaunchKernelGGL(hash_kernel,    dim3(2048), dim3(256), 0, stream, qk, rot, bucket_ws, bucket_out, ninv_ws);
    hipLaunchKernelGGL(sort_kernel,    dim3(64),   dim3(256), 0, stream, bucket_ws, st);
    hipLaunchKernelGGL(attn_kernel,    dim3(4096), dim3(256), 0, stream, qk, v, st, ninv_ws, logits_ws, o_ws, obf16);
    hipLaunchKernelGGL(combine_kernel, dim3(4096), dim3(256), 0, stream, logits_ws, o_ws, out, obf16);
}

// Round 14
// 180.904 us; speedup vs baseline: 1.1400x; 1.1400x over previous
//
#include <hip/hip_runtime.h>
#include <hip/hip_bf16.h>

#define BB 8
#define SS 4096
#define DD 128
#define HH 8
#define NBUCK 64
#define CHUNKSZ 64
#define NCHUNK 512      // HH*SS/CHUNKSZ
#define HSTOT 32768     // HH*SS
#define ROWB 272        // bf16 tile row stride in bytes (128*2 + 16 pad)

typedef __attribute__((ext_vector_type(8))) short short8_t;   // 8 bf16 = 4 VGPR
typedef __attribute__((ext_vector_type(4))) float f32x4;

static __device__ __forceinline__ unsigned short f2bf(float f) {
    __hip_bfloat16 h = __float2bfloat16(f);
    return *reinterpret_cast<unsigned short*>(&h);
}
static __device__ __forceinline__ unsigned int pk2bf(float lo, float hi) {
    __hip_bfloat162 h = __float22bfloat162_rn(make_float2(lo, hi));   // v_cvt_pk_bf16_f32
    return *reinterpret_cast<unsigned int*>(&h);
}
static __device__ __forceinline__ float bf2f(unsigned short u) {
    return __uint_as_float(((unsigned int)u) << 16);
}

// ---------------- Kernel A: LSH hashing (register-resident) ------------------
// R9 structure + R12 XCD batch pinning (measured best: ~60us).
// R10 MFMA variant was slower (latency-bound); R13 reg-cache variant spilled.
__global__ __launch_bounds__(256) void hash_kernel(
    const float* __restrict__ qk, const float* __restrict__ rot,
    unsigned char* __restrict__ bucket_ws, float* __restrict__ bucket_out)
{
    const int tid = threadIdx.x;
    const int bid = blockIdx.x;            // 0..2047 = tile(5) | h(3) | b(3)
    const int b   = bid & 7;               // XCD-pinned batch
    const int h   = (bid >> 3) & 7;
    const int t0  = (bid >> 6) * 128;
    const int tg  = tid >> 3;              // token group 0..31 (4 tokens each)
    const int jq  = tid & 7;               // j-quad 0..7 (4 columns each)

    const float* qbase = qk + ((size_t)b * SS + t0 + tg * 4) * DD;
    const float* rbase = rot + h * 32 + jq * 4;   // rot[f][h][j], f-stride 256

    float acc[4][4];
    #pragma unroll
    for (int r = 0; r < 4; ++r)
        #pragma unroll
        for (int j = 0; j < 4; ++j) acc[r][j] = 0.f;

    for (int c = 0; c < 16; ++c) {         // f in chunks of 8
        float4 qv[4][2];
        #pragma unroll
        for (int r = 0; r < 4; ++r) {
            qv[r][0] = *reinterpret_cast<const float4*>(qbase + r * DD + c * 8);
            qv[r][1] = *reinterpret_cast<const float4*>(qbase + r * DD + c * 8 + 4);
        }
        float4 rv[8];
        #pragma unroll
        for (int ff = 0; ff < 8; ++ff)
            rv[ff] = *reinterpret_cast<const float4*>(rbase + (size_t)(c * 8 + ff) * (HH * 32));
        #pragma unroll
        for (int ff = 0; ff < 8; ++ff) {
            #pragma unroll
            for (int r = 0; r < 4; ++r) {
                const float4 qh = qv[r][ff >> 2];
                const float qs = (ff & 2) ? ((ff & 1) ? qh.w : qh.z)
                                          : ((ff & 1) ? qh.y : qh.x);
                acc[r][0] = fmaf(qs, rv[ff].x, acc[r][0]);
                acc[r][1] = fmaf(qs, rv[ff].y, acc[r][1]);
                acc[r][2] = fmaf(qs, rv[ff].z, acc[r][2]);
                acc[r][3] = fmaf(qs, rv[ff].w, acc[r][3]);
            }
        }
    }

    const float TAU = 0.01f;
    #pragma unroll
    for (int r = 0; r < 4; ++r) {
        float bv = -3.0e38f; int bi = 0;
        #pragma unroll
        for (int j = 0; j < 4; ++j) {
            float v = acc[r][j];
            if (v > bv) { bv = v; bi = jq * 4 + j; }
        }
        #pragma unroll
        for (int j = 0; j < 4; ++j) {
            float v = -acc[r][j];
            if (v > bv) { bv = v; bi = 32 + jq * 4 + j; }
        }
        #pragma unroll
        for (int off = 1; off < 8; off <<= 1) {
            float ov = __shfl_xor(bv, off);
            int   oi = __shfl_xor(bi, off);
            if (ov > bv || (ov == bv && oi < bi)) { bv = ov; bi = oi; }
        }
        const float thrv = bv - TAU;
        int cnt = 0;
        #pragma unroll
        for (int j = 0; j < 4; ++j) {
            cnt += (acc[r][j]  > thrv) ? 1 : 0;
            cnt += (-acc[r][j] > thrv) ? 1 : 0;
        }
        #pragma unroll
        for (int off = 1; off < 8; off <<= 1) cnt += __shfl_xor(cnt, off);

        const int t = t0 + tg * 4 + r;
        if (cnt > 1) {
            const float* qrow = qk + ((size_t)b * SS + t) * DD;
            double bvd = -1.0e300; int bid2 = 64;
            #pragma unroll
            for (int j = 0; j < 4; ++j) {
                const bool fp = (acc[r][j] > thrv);
                const bool fn = (-acc[r][j] > thrv);
                if (fp || fn) {
                    const float* rcol = rot + h * 32 + jq * 4 + j;
                    double a = 0.0;
                    for (int f = 0; f < DD; ++f)
                        a = fma((double)qrow[f], (double)rcol[(size_t)f * (HH * 32)], a);
                    if (fp &&  a > bvd)                         { bvd = a;  bid2 = jq * 4 + j; }
                    if (fn && (-a > bvd ||
                               (-a == bvd && 32 + jq * 4 + j < bid2))) { bvd = -a; bid2 = 32 + jq * 4 + j; }
                }
            }
            #pragma unroll
            for (int off = 1; off < 8; off <<= 1) {
                double ov = __shfl_xor(bvd, off);
                int    oi = __shfl_xor(bid2, off);
                if (ov > bvd || (ov == bvd && oi < bid2)) { bvd = ov; bid2 = oi; }
            }
            bi = bid2;
        }
        if (jq == 0) {
            const size_t o = ((size_t)b * HH + h) * SS + t;
            bucket_ws[o]  = (unsigned char)bi;
            bucket_out[o] = (float)(bi + h * NBUCK);
        }
    }
}

// ---------------- Kernel B: stable counting sort per (b,h) -------------------
__global__ __launch_bounds__(256) void sort_kernel(
    const unsigned char* __restrict__ bucket_ws, int* __restrict__ st)
{
    __shared__ unsigned int hist[256 * 65];   // padded stride 65
    __shared__ unsigned int totals[64];
    const int tid = threadIdx.x;
    const int bh  = blockIdx.x;               // 0..63 = b*8+h

    unsigned int* hrow = &hist[tid * 65];
    #pragma unroll
    for (int j = 0; j < 65; ++j) hrow[j] = 0u;

    const uint4 raw = *reinterpret_cast<const uint4*>(bucket_ws + (size_t)bh * SS + tid * 16);
    unsigned int w[4] = {raw.x, raw.y, raw.z, raw.w};

    #pragma unroll
    for (int c = 0; c < 16; ++c) {
        unsigned int bk = (w[c >> 2] >> ((c & 3) * 8)) & 255u;
        hrow[bk] += 1u;
    }
    __syncthreads();

    if (tid < 64) {
        unsigned int run = 0;
        for (int c2 = 0; c2 < 256; ++c2) {
            unsigned int x = hist[c2 * 65 + tid];
            hist[c2 * 65 + tid] = run;
            run += x;
        }
        totals[tid] = run;
    }
    __syncthreads();
    if (tid == 0) {
        unsigned int base = 0;
        for (int k = 0; k < 64; ++k) { unsigned int x = totals[k]; totals[k] = base; base += x; }
    }
    __syncthreads();

    int* dst = st + (size_t)bh * SS;
    #pragma unroll
    for (int c = 0; c < 16; ++c) {
        unsigned int bk = (w[c >> 2] >> ((c & 3) * 8)) & 255u;
        unsigned int pos = totals[bk] + hrow[bk];
        hrow[bk] += 1u;
        dst[pos] = tid * 16 + c;
    }
}

// ---------------- Kernel C: chunked attention via bf16 MFMA ------------------
// R12 structure (measured 96us): LDS 36864 -> 4 blocks/CU, XCD batch pinning,
// tks/psums in LDS, setprio on MFMA clusters, V in two 64-dim phases.
// R14 single change: V-phase-0 gather loads issue at KERNEL START (indices
// straight from L2-hot st[]), hiding their latency under K-stage+QK^T+softmax.
// R13 lesson: no tight VGPR caps / no reg-cached index arrays (spills).
__global__ __launch_bounds__(256, 4) void attn_kernel(
    const float* __restrict__ qk, const float* __restrict__ vv,
    const int* __restrict__ st, float* __restrict__ logits_ws,
    void* __restrict__ o_ws, const int obf16)
{
    __shared__ __align__(16) char smem[36864];
    char*  Kb    = smem;
    char*  Pb    = smem;                       // after Kb retired
    char*  Vt    = smem + 17408;               // 64 dim-rows x 272 B
    int*   tks   = (int*)(smem + 34816);
    float* ninv  = (float*)(smem + 35328);
    float* psums = (float*)(smem + 35840);

    const int tid = threadIdx.x;
    const int bc  = blockIdx.x;
    const int b   = bc & 7;                    // XCD-pinned batch
    const int c   = bc >> 3;                   // chunk 0..511
    const int h   = c >> 6;
    const int cprev = (c == 0) ? (NCHUNK - 1) : (c - 1);
    const int* stb  = st + (size_t)b * HSTOT;

    // ---- V phase-0 prefetch: issue FIRST (T14 deepened) ---------------------
    const int kp = tid & 63;                   // token pair 2kp, 2kp+1
    const int db = tid >> 6;                   // dim sub-block (16 dims)
    const int idxa = 2 * kp, idxb = 2 * kp + 1;
    const int tva = stb[(size_t)((idxa < 64) ? c : cprev) * CHUNKSZ + (idxa & 63)];
    const int tvb = stb[(size_t)((idxb < 64) ? c : cprev) * CHUNKSZ + (idxb & 63)];
    const float* vra = vv + ((size_t)b * SS + tva) * DD + db * 16;
    const float* vrb = vv + ((size_t)b * SS + tvb) * DD + db * 16;
    float4 va[4], vbr[4];
    #pragma unroll
    for (int i = 0; i < 4; ++i) {
        va[i]  = *reinterpret_cast<const float4*>(vra + i * 4);
        vbr[i] = *reinterpret_cast<const float4*>(vrb + i * 4);
    }

    // own K-row index straight from global (L2-hot) -- off the barrier path
    const int rowk  = tid >> 1, halfk = tid & 1;
    const int t_mine = stb[(size_t)((rowk < 64) ? c : cprev) * CHUNKSZ + (rowk & 63)];

    if (tid < 128) {                           // LDS copy for later phases
        tks[tid] = stb[(size_t)((tid < 64) ? c : cprev) * CHUNKSZ + (tid & 63)];
    }

    // ---- stage K (raw qk rows, bf16) + sum-of-squares -----------------------
    {
        const float* srow = qk + ((size_t)b * SS + t_mine) * DD + halfk * 64;
        char* krow = Kb + (size_t)rowk * ROWB + halfk * 128;
        float ss = 0.f;
        #pragma unroll
        for (int i = 0; i < 8; ++i) {
            float4 v0 = *reinterpret_cast<const float4*>(srow + i * 8);
            float4 v1 = *reinterpret_cast<const float4*>(srow + i * 8 + 4);
            ss = fmaf(v0.x, v0.x, ss); ss = fmaf(v0.y, v0.y, ss);
            ss = fmaf(v0.z, v0.z, ss); ss = fmaf(v0.w, v0.w, ss);
            ss = fmaf(v1.x, v1.x, ss); ss = fmaf(v1.y, v1.y, ss);
            ss = fmaf(v1.z, v1.z, ss); ss = fmaf(v1.w, v1.w, ss);
            uint4 pk;
            pk.x = pk2bf(v0.x, v0.y); pk.y = pk2bf(v0.z, v0.w);
            pk.z = pk2bf(v1.x, v1.y); pk.w = pk2bf(v1.z, v1.w);
            *reinterpret_cast<uint4*>(krow + i * 16) = pk;
        }
        psums[tid] = ss;
    }
    __syncthreads();
    if (tid < 128) ninv[tid] = rsqrtf(psums[2 * tid] + psums[2 * tid + 1] + 1e-6f);
    __syncthreads();

    const int w  = tid >> 6;     // wave id: q-tile rows 16w..16w+15
    const int ln = tid & 63;
    const int cc = ln & 15;      // fragment col lane
    const int g  = ln >> 4;      // fragment k-group / row-group

    // ---- QK^T ---------------------------------------------------------------
    short8_t aq[4];
    #pragma unroll
    for (int ks = 0; ks < 4; ++ks)
        aq[ks] = *reinterpret_cast<const short8_t*>(Kb + (size_t)(16 * w + cc) * ROWB + ks * 64 + g * 16);

    f32x4 acc[8];
    __builtin_amdgcn_s_setprio(1);
    #pragma unroll
    for (int j = 0; j < 8; ++j) {
        acc[j] = (f32x4){0.f, 0.f, 0.f, 0.f};
        #pragma unroll
        for (int ks = 0; ks < 4; ++ks) {
            short8_t bk = *reinterpret_cast<const short8_t*>(Kb + (size_t)(16 * j + cc) * ROWB + ks * 64 + g * 16);
            acc[j] = __builtin_amdgcn_mfma_f32_16x16x32_bf16(aq[ks], bk, acc[j], 0, 0, 0);
        }
    }
    __builtin_amdgcn_s_setprio(0);

    // ---- softmax (regs) -----------------------------------------------------
    const float SCALE = 0.088388347648318447f;   // 128^-0.5
    float lse[4];
    float pr[8][4];
    #pragma unroll
    for (int jr = 0; jr < 4; ++jr) {
        const int q  = 16 * w + 4 * g + jr;
        const int tq = tks[q];
        float m = -3.0e38f;
        #pragma unroll
        for (int j = 0; j < 8; ++j) {
            const int k = 16 * j + cc;
            float val = acc[j][jr] * (ninv[k] * SCALE);
            if (tks[k] == tq) val = -1e5f;
            pr[j][jr] = val;
            m = fmaxf(m, val);
        }
        #pragma unroll
        for (int off = 1; off < 16; off <<= 1) m = fmaxf(m, __shfl_xor(m, off));
        float ssum = 0.f;
        #pragma unroll
        for (int j = 0; j < 8; ++j) { float ex = expf(pr[j][jr] - m); pr[j][jr] = ex; ssum += ex; }
        #pragma unroll
        for (int off = 1; off < 16; off <<= 1) ssum += __shfl_xor(ssum, off);
        const float inv = 1.0f / ssum;
        #pragma unroll
        for (int j = 0; j < 8; ++j) pr[j][jr] *= inv;
        lse[jr] = m + logf(ssum);
    }

    __syncthreads();   // all waves done reading Kb; Pb/Vt may be written

    // ---- write P (bf16) -----------------------------------------------------
    #pragma unroll
    for (int jr = 0; jr < 4; ++jr) {
        const int q = 16 * w + 4 * g + jr;
        #pragma unroll
        for (int j = 0; j < 8; ++j)
            *reinterpret_cast<unsigned short*>(Pb + (size_t)q * ROWB + (16 * j + cc) * 2) = f2bf(pr[j][jr]);
    }
    if (cc == 0) {
        #pragma unroll
        for (int jr = 0; jr < 4; ++jr) {
            const int q = 16 * w + 4 * g + jr;
            logits_ws[((size_t)b * HH + h) * SS + tks[q]] = lse[jr];
        }
    }
    // ---- write V phase 0 to Vt ----------------------------------------------
    {
        const float* fa = reinterpret_cast<const float*>(va);
        const float* fb = reinterpret_cast<const float*>(vbr);
        #pragma unroll
        for (int i = 0; i < 16; ++i) {
            const int dl = db * 16 + i;
            *reinterpret_cast<unsigned int*>(Vt + (size_t)dl * ROWB + kp * 4) = pk2bf(fa[i], fb[i]);
        }
    }
    // ---- prefetch V phase 1 (dims 64..127) into regs (T14 split) ------------
    #pragma unroll
    for (int i = 0; i < 4; ++i) {
        va[i]  = *reinterpret_cast<const float4*>(vra + 64 + i * 4);
        vbr[i] = *reinterpret_cast<const float4*>(vrb + 64 + i * 4);
    }
    __syncthreads();   // Pb + Vt(phase 0) visible

    // ---- PV -----------------------------------------------------------------
    short8_t pa[4];
    #pragma unroll
    for (int ks = 0; ks < 4; ++ks)
        pa[ks] = *reinterpret_cast<const short8_t*>(Pb + (size_t)(16 * w + cc) * ROWB + ks * 64 + g * 16);

    f32x4 oacc[8];
    __builtin_amdgcn_s_setprio(1);
    #pragma unroll
    for (int dt = 0; dt < 4; ++dt) {       // phase A: output dims 0..63
        oacc[dt] = (f32x4){0.f, 0.f, 0.f, 0.f};
        #pragma unroll
        for (int ks = 0; ks < 4; ++ks) {
            short8_t vb = *reinterpret_cast<const short8_t*>(Vt + (size_t)(16 * dt + cc) * ROWB + ks * 64 + g * 16);
            oacc[dt] = __builtin_amdgcn_mfma_f32_16x16x32_bf16(pa[ks], vb, oacc[dt], 0, 0, 0);
        }
    }
    __builtin_amdgcn_s_setprio(0);
    __syncthreads();   // phase-A reads of Vt done

    // ---- write V phase 1 to Vt ----------------------------------------------
    {
        const float* fa = reinterpret_cast<const float*>(va);
        const float* fb = reinterpret_cast<const float*>(vbr);
        #pragma unroll
        for (int i = 0; i < 16; ++i) {
            const int dl = db * 16 + i;
            *reinterpret_cast<unsigned int*>(Vt + (size_t)dl * ROWB + kp * 4) = pk2bf(fa[i], fb[i]);
        }
    }
    __syncthreads();

    __builtin_amdgcn_s_setprio(1);
    #pragma unroll
    for (int dt = 4; dt < 8; ++dt) {       // phase B: output dims 64..127
        oacc[dt] = (f32x4){0.f, 0.f, 0.f, 0.f};
        #pragma unroll
        for (int ks = 0; ks < 4; ++ks) {
            short8_t vb = *reinterpret_cast<const short8_t*>(Vt + (size_t)(16 * (dt - 4) + cc) * ROWB + ks * 64 + g * 16);
            oacc[dt] = __builtin_amdgcn_mfma_f32_16x16x32_bf16(pa[ks], vb, oacc[dt], 0, 0, 0);
        }
    }
    __builtin_amdgcn_s_setprio(0);

    // ---- scatter per-round outputs ------------------------------------------
    #pragma unroll
    for (int jr = 0; jr < 4; ++jr) {
        const int q = 16 * w + 4 * g + jr;
        const int t = tks[q];
        const size_t base = (((size_t)b * HH + h) * SS + t) * DD + cc;
        if (!obf16) {
            float* op = (float*)o_ws;
            #pragma unroll
            for (int dt = 0; dt < 8; ++dt) op[base + 16 * dt] = oacc[dt][jr];
        } else {
            unsigned short* op = (unsigned short*)o_ws;
            #pragma unroll
            for (int dt = 0; dt < 8; ++dt) op[base + 16 * dt] = f2bf(oacc[dt][jr]);
        }
    }
}

// ---------------- Kernel D: softmax-combine over hash rounds -----------------
__global__ __launch_bounds__(256) void combine_kernel(
    const float* __restrict__ logits_ws, const void* __restrict__ o_ws,
    float* __restrict__ outp, const int obf16)
{
    const int gid = blockIdx.x * 256 + threadIdx.x;
    const int row = gid >> 5;     // (b,t)
    const int seg = gid & 31;     // 4-float segment of D
    const int b = row >> 12;
    const int t = row & 4095;

    float l[8];
    float m = -3.0e38f;
    #pragma unroll
    for (int hh = 0; hh < 8; ++hh) {
        l[hh] = logits_ws[((size_t)b * HH + hh) * SS + t];
        m = fmaxf(m, l[hh]);
    }
    float ssum = 0.f;
    #pragma unroll
    for (int hh = 0; hh < 8; ++hh) { l[hh] = expf(l[hh] - m); ssum += l[hh]; }
    const float inv = 1.0f / ssum;

    float a0 = 0.f, a1 = 0.f, a2 = 0.f, a3 = 0.f;
    #pragma unroll
    for (int hh = 0; hh < 8; ++hh) {
        const float wgt = l[hh] * inv;
        const size_t base = (((size_t)b * HH + hh) * SS + t) * DD + seg * 4;
        if (!obf16) {
            float4 ov = *reinterpret_cast<const float4*>((const float*)o_ws + base);
            a0 = fmaf(wgt, ov.x, a0); a1 = fmaf(wgt, ov.y, a1);
            a2 = fmaf(wgt, ov.z, a2); a3 = fmaf(wgt, ov.w, a3);
        } else {
            uint2 u = *reinterpret_cast<const uint2*>((const unsigned short*)o_ws + base);
            a0 = fmaf(wgt, bf2f((unsigned short)(u.x & 0xffffu)), a0);
            a1 = fmaf(wgt, bf2f((unsigned short)(u.x >> 16)), a1);
            a2 = fmaf(wgt, bf2f((unsigned short)(u.y & 0xffffu)), a2);
            a3 = fmaf(wgt, bf2f((unsigned short)(u.y >> 16)), a3);
        }
    }
    *reinterpret_cast<float4*>(outp + ((size_t)b * SS + t) * DD + seg * 4) =
        make_float4(a0, a1, a2, a3);
}

extern "C" void kernel_launch(void* const* d_in, const int* in_sizes, int n_in,
                              void* d_out, int out_size, void* d_ws, size_t ws_size,
                              hipStream_t stream) {
    const float* qk  = (const float*)d_in[0];
    const float* v   = (const float*)d_in[1];
    const float* rot = (const float*)d_in[2];

    float* out        = (float*)d_out;
    float* bucket_out = out + (size_t)BB * SS * DD;   // buckets written as f32

    char* ws = (char*)d_ws;
    int*            st        = (int*)ws;                              // 1,048,576 B
    unsigned char*  bucket_ws = (unsigned char*)(ws + 1048576);        //   262,144 B
    float*          logits_ws = (float*)(ws + 1048576 + 262144);       // 1,048,576 B
    void*           o_ws      = (void*)(ws + 2359296);                 // big scratch

    const int obf16 = 1;   // bf16 o-scratch: halves attn WRITE + combine read traffic

    hipLaunchKernelGGL(hash_kernel,    dim3(2048), dim3(256), 0, stream, qk, rot, bucket_ws, bucket_out);
    hipLaunchKernelGGL(sort_kernel,    dim3(64),   dim3(256), 0, stream, bucket_ws, st);
    hipLaunchKernelGGL(attn_kernel,    dim3(4096), dim3(256), 0, stream, qk, v, st, logits_ws, o_ws, obf16);
    hipLaunchKernelGGL(combine_kernel, dim3(4096), dim3(256), 0, stream, logits_ws, o_ws, out, obf16);
}

// Round 15
// 179.660 us; speedup vs baseline: 1.1479x; 1.0069x over previous
//
#include <hip/hip_runtime.h>
#include <hip/hip_bf16.h>

#define BB 8
#define SS 4096
#define DD 128
#define HH 8
#define NBUCK 64
#define CHUNKSZ 64
#define NCHUNK 512      // HH*SS/CHUNKSZ
#define HSTOT 32768     // HH*SS
#define ROWB 272        // bf16 tile row stride in bytes (128*2 + 16 pad)

typedef __attribute__((ext_vector_type(8))) short short8_t;   // 8 bf16 = 4 VGPR
typedef __attribute__((ext_vector_type(4))) float f32x4;

static __device__ __forceinline__ unsigned short f2bf(float f) {
    __hip_bfloat16 h = __float2bfloat16(f);
    return *reinterpret_cast<unsigned short*>(&h);
}
static __device__ __forceinline__ unsigned int pk2bf(float lo, float hi) {
    __hip_bfloat162 h = __float22bfloat162_rn(make_float2(lo, hi));   // v_cvt_pk_bf16_f32
    return *reinterpret_cast<unsigned int*>(&h);
}
static __device__ __forceinline__ float bf2f(unsigned short u) {
    return __uint_as_float(((unsigned int)u) << 16);
}

// ---------------- Kernel A: LSH hashing (register-resident) ------------------
// R9 structure + R12 XCD batch pinning (measured best: ~60us).
// R10 MFMA variant was slower (latency-bound); R13 reg-cache variant spilled.
// Bit-exactness-critical (buckets output): do not alter FMA order.
__global__ __launch_bounds__(256) void hash_kernel(
    const float* __restrict__ qk, const float* __restrict__ rot,
    unsigned char* __restrict__ bucket_ws, float* __restrict__ bucket_out)
{
    const int tid = threadIdx.x;
    const int bid = blockIdx.x;            // 0..2047 = tile(5) | h(3) | b(3)
    const int b   = bid & 7;               // XCD-pinned batch
    const int h   = (bid >> 3) & 7;
    const int t0  = (bid >> 6) * 128;
    const int tg  = tid >> 3;              // token group 0..31 (4 tokens each)
    const int jq  = tid & 7;               // j-quad 0..7 (4 columns each)

    const float* qbase = qk + ((size_t)b * SS + t0 + tg * 4) * DD;
    const float* rbase = rot + h * 32 + jq * 4;   // rot[f][h][j], f-stride 256

    float acc[4][4];
    #pragma unroll
    for (int r = 0; r < 4; ++r)
        #pragma unroll
        for (int j = 0; j < 4; ++j) acc[r][j] = 0.f;

    for (int c = 0; c < 16; ++c) {         // f in chunks of 8
        float4 qv[4][2];
        #pragma unroll
        for (int r = 0; r < 4; ++r) {
            qv[r][0] = *reinterpret_cast<const float4*>(qbase + r * DD + c * 8);
            qv[r][1] = *reinterpret_cast<const float4*>(qbase + r * DD + c * 8 + 4);
        }
        float4 rv[8];
        #pragma unroll
        for (int ff = 0; ff < 8; ++ff)
            rv[ff] = *reinterpret_cast<const float4*>(rbase + (size_t)(c * 8 + ff) * (HH * 32));
        #pragma unroll
        for (int ff = 0; ff < 8; ++ff) {
            #pragma unroll
            for (int r = 0; r < 4; ++r) {
                const float4 qh = qv[r][ff >> 2];
                const float qs = (ff & 2) ? ((ff & 1) ? qh.w : qh.z)
                                          : ((ff & 1) ? qh.y : qh.x);
                acc[r][0] = fmaf(qs, rv[ff].x, acc[r][0]);
                acc[r][1] = fmaf(qs, rv[ff].y, acc[r][1]);
                acc[r][2] = fmaf(qs, rv[ff].z, acc[r][2]);
                acc[r][3] = fmaf(qs, rv[ff].w, acc[r][3]);
            }
        }
    }

    const float TAU = 0.01f;
    #pragma unroll
    for (int r = 0; r < 4; ++r) {
        float bv = -3.0e38f; int bi = 0;
        #pragma unroll
        for (int j = 0; j < 4; ++j) {
            float v = acc[r][j];
            if (v > bv) { bv = v; bi = jq * 4 + j; }
        }
        #pragma unroll
        for (int j = 0; j < 4; ++j) {
            float v = -acc[r][j];
            if (v > bv) { bv = v; bi = 32 + jq * 4 + j; }
        }
        #pragma unroll
        for (int off = 1; off < 8; off <<= 1) {
            float ov = __shfl_xor(bv, off);
            int   oi = __shfl_xor(bi, off);
            if (ov > bv || (ov == bv && oi < bi)) { bv = ov; bi = oi; }
        }
        const float thrv = bv - TAU;
        int cnt = 0;
        #pragma unroll
        for (int j = 0; j < 4; ++j) {
            cnt += (acc[r][j]  > thrv) ? 1 : 0;
            cnt += (-acc[r][j] > thrv) ? 1 : 0;
        }
        #pragma unroll
        for (int off = 1; off < 8; off <<= 1) cnt += __shfl_xor(cnt, off);

        const int t = t0 + tg * 4 + r;
        if (cnt > 1) {
            const float* qrow = qk + ((size_t)b * SS + t) * DD;
            double bvd = -1.0e300; int bid2 = 64;
            #pragma unroll
            for (int j = 0; j < 4; ++j) {
                const bool fp = (acc[r][j] > thrv);
                const bool fn = (-acc[r][j] > thrv);
                if (fp || fn) {
                    const float* rcol = rot + h * 32 + jq * 4 + j;
                    double a = 0.0;
                    for (int f = 0; f < DD; ++f)
                        a = fma((double)qrow[f], (double)rcol[(size_t)f * (HH * 32)], a);
                    if (fp &&  a > bvd)                         { bvd = a;  bid2 = jq * 4 + j; }
                    if (fn && (-a > bvd ||
                               (-a == bvd && 32 + jq * 4 + j < bid2))) { bvd = -a; bid2 = 32 + jq * 4 + j; }
                }
            }
            #pragma unroll
            for (int off = 1; off < 8; off <<= 1) {
                double ov = __shfl_xor(bvd, off);
                int    oi = __shfl_xor(bid2, off);
                if (ov > bvd || (ov == bvd && oi < bid2)) { bvd = ov; bid2 = oi; }
            }
            bi = bid2;
        }
        if (jq == 0) {
            const size_t o = ((size_t)b * HH + h) * SS + t;
            bucket_ws[o]  = (unsigned char)bi;
            bucket_out[o] = (float)(bi + h * NBUCK);
        }
    }
}

// ---------------- Kernel B: stable counting sort per (b,h) -------------------
__global__ __launch_bounds__(256) void sort_kernel(
    const unsigned char* __restrict__ bucket_ws, int* __restrict__ st)
{
    __shared__ unsigned int hist[256 * 65];   // padded stride 65
    __shared__ unsigned int totals[64];
    const int tid = threadIdx.x;
    const int bh  = blockIdx.x;               // 0..63 = b*8+h

    unsigned int* hrow = &hist[tid * 65];
    #pragma unroll
    for (int j = 0; j < 65; ++j) hrow[j] = 0u;

    const uint4 raw = *reinterpret_cast<const uint4*>(bucket_ws + (size_t)bh * SS + tid * 16);
    unsigned int w[4] = {raw.x, raw.y, raw.z, raw.w};

    #pragma unroll
    for (int c = 0; c < 16; ++c) {
        unsigned int bk = (w[c >> 2] >> ((c & 3) * 8)) & 255u;
        hrow[bk] += 1u;
    }
    __syncthreads();

    if (tid < 64) {
        unsigned int run = 0;
        for (int c2 = 0; c2 < 256; ++c2) {
            unsigned int x = hist[c2 * 65 + tid];
            hist[c2 * 65 + tid] = run;
            run += x;
        }
        totals[tid] = run;
    }
    __syncthreads();
    if (tid == 0) {
        unsigned int base = 0;
        for (int k = 0; k < 64; ++k) { unsigned int x = totals[k]; totals[k] = base; base += x; }
    }
    __syncthreads();

    int* dst = st + (size_t)bh * SS;
    #pragma unroll
    for (int c = 0; c < 16; ++c) {
        unsigned int bk = (w[c >> 2] >> ((c & 3) * 8)) & 255u;
        unsigned int pos = totals[bk] + hrow[bk];
        hrow[bk] += 1u;
        dst[pos] = tid * 16 + c;
    }
}

// ---------------- Kernel C: chunked attention via bf16 MFMA ------------------
// R12 structure: LDS 36864 -> 4 blocks/CU, XCD batch pinning, setprio (T5),
// V in two 64-dim phases with early prefetch (T14).
// R15: expf->__expf (v_exp_f32), logf->__logf, ninv pre-scaled by 128^-0.5 --
// softmax was the largest VALU block (32 libm expf/thread ~15 ops each).
__global__ __launch_bounds__(256, 4) void attn_kernel(
    const float* __restrict__ qk, const float* __restrict__ vv,
    const int* __restrict__ st, float* __restrict__ logits_ws,
    void* __restrict__ o_ws, const int obf16)
{
    __shared__ __align__(16) char smem[36864];
    char*  Kb    = smem;
    char*  Pb    = smem;                       // after Kb retired
    char*  Vt    = smem + 17408;               // 64 dim-rows x 272 B
    int*   tks   = (int*)(smem + 34816);
    float* ninv  = (float*)(smem + 35328);
    float* psums = (float*)(smem + 35840);

    const int tid = threadIdx.x;
    const int bc  = blockIdx.x;
    const int b   = bc & 7;                    // XCD-pinned batch
    const int c   = bc >> 3;                   // chunk 0..511
    const int h   = c >> 6;
    const int cprev = (c == 0) ? (NCHUNK - 1) : (c - 1);
    const int* stb  = st + (size_t)b * HSTOT;

    // ---- V phase-0 prefetch: issue FIRST (T14) ------------------------------
    const int kp = tid & 63;                   // token pair 2kp, 2kp+1
    const int db = tid >> 6;                   // dim sub-block (16 dims)
    const int idxa = 2 * kp, idxb = 2 * kp + 1;
    const int tva = stb[(size_t)((idxa < 64) ? c : cprev) * CHUNKSZ + (idxa & 63)];
    const int tvb = stb[(size_t)((idxb < 64) ? c : cprev) * CHUNKSZ + (idxb & 63)];
    const float* vra = vv + ((size_t)b * SS + tva) * DD + db * 16;
    const float* vrb = vv + ((size_t)b * SS + tvb) * DD + db * 16;
    float4 va[4], vbr[4];
    #pragma unroll
    for (int i = 0; i < 4; ++i) {
        va[i]  = *reinterpret_cast<const float4*>(vra + i * 4);
        vbr[i] = *reinterpret_cast<const float4*>(vrb + i * 4);
    }

    // own K-row index straight from global (L2-hot) -- off the barrier path
    const int rowk  = tid >> 1, halfk = tid & 1;
    const int t_mine = stb[(size_t)((rowk < 64) ? c : cprev) * CHUNKSZ + (rowk & 63)];

    if (tid < 128) {                           // LDS copy for later phases
        tks[tid] = stb[(size_t)((tid < 64) ? c : cprev) * CHUNKSZ + (tid & 63)];
    }

    // ---- stage K (raw qk rows, bf16) + sum-of-squares -----------------------
    {
        const float* srow = qk + ((size_t)b * SS + t_mine) * DD + halfk * 64;
        char* krow = Kb + (size_t)rowk * ROWB + halfk * 128;
        float ss = 0.f;
        #pragma unroll
        for (int i = 0; i < 8; ++i) {
            float4 v0 = *reinterpret_cast<const float4*>(srow + i * 8);
            float4 v1 = *reinterpret_cast<const float4*>(srow + i * 8 + 4);
            ss = fmaf(v0.x, v0.x, ss); ss = fmaf(v0.y, v0.y, ss);
            ss = fmaf(v0.z, v0.z, ss); ss = fmaf(v0.w, v0.w, ss);
            ss = fmaf(v1.x, v1.x, ss); ss = fmaf(v1.y, v1.y, ss);
            ss = fmaf(v1.z, v1.z, ss); ss = fmaf(v1.w, v1.w, ss);
            uint4 pk;
            pk.x = pk2bf(v0.x, v0.y); pk.y = pk2bf(v0.z, v0.w);
            pk.z = pk2bf(v1.x, v1.y); pk.w = pk2bf(v1.z, v1.w);
            *reinterpret_cast<uint4*>(krow + i * 16) = pk;
        }
        psums[tid] = ss;
    }
    __syncthreads();
    if (tid < 128)    // pre-scaled by 128^-0.5 (saves a mult per use)
        ninv[tid] = rsqrtf(psums[2 * tid] + psums[2 * tid + 1] + 1e-6f) * 0.088388347648318447f;
    __syncthreads();

    const int w  = tid >> 6;     // wave id: q-tile rows 16w..16w+15
    const int ln = tid & 63;
    const int cc = ln & 15;      // fragment col lane
    const int g  = ln >> 4;      // fragment k-group / row-group

    // ---- QK^T ---------------------------------------------------------------
    short8_t aq[4];
    #pragma unroll
    for (int ks = 0; ks < 4; ++ks)
        aq[ks] = *reinterpret_cast<const short8_t*>(Kb + (size_t)(16 * w + cc) * ROWB + ks * 64 + g * 16);

    f32x4 acc[8];
    __builtin_amdgcn_s_setprio(1);
    #pragma unroll
    for (int j = 0; j < 8; ++j) {
        acc[j] = (f32x4){0.f, 0.f, 0.f, 0.f};
        #pragma unroll
        for (int ks = 0; ks < 4; ++ks) {
            short8_t bk = *reinterpret_cast<const short8_t*>(Kb + (size_t)(16 * j + cc) * ROWB + ks * 64 + g * 16);
            acc[j] = __builtin_amdgcn_mfma_f32_16x16x32_bf16(aq[ks], bk, acc[j], 0, 0, 0);
        }
    }
    __builtin_amdgcn_s_setprio(0);

    // ---- softmax (regs, fast-math exp/log) ----------------------------------
    float lse[4];
    float pr[8][4];
    #pragma unroll
    for (int jr = 0; jr < 4; ++jr) {
        const int q  = 16 * w + 4 * g + jr;
        const int tq = tks[q];
        float m = -3.0e38f;
        #pragma unroll
        for (int j = 0; j < 8; ++j) {
            const int k = 16 * j + cc;
            float val = acc[j][jr] * ninv[k];
            if (tks[k] == tq) val = -1e5f;
            pr[j][jr] = val;
            m = fmaxf(m, val);
        }
        #pragma unroll
        for (int off = 1; off < 16; off <<= 1) m = fmaxf(m, __shfl_xor(m, off));
        float ssum = 0.f;
        #pragma unroll
        for (int j = 0; j < 8; ++j) { float ex = __expf(pr[j][jr] - m); pr[j][jr] = ex; ssum += ex; }
        #pragma unroll
        for (int off = 1; off < 16; off <<= 1) ssum += __shfl_xor(ssum, off);
        const float inv = 1.0f / ssum;
        #pragma unroll
        for (int j = 0; j < 8; ++j) pr[j][jr] *= inv;
        lse[jr] = m + __logf(ssum);
    }

    __syncthreads();   // all waves done reading Kb; Pb/Vt may be written

    // ---- write P (bf16) -----------------------------------------------------
    #pragma unroll
    for (int jr = 0; jr < 4; ++jr) {
        const int q = 16 * w + 4 * g + jr;
        #pragma unroll
        for (int j = 0; j < 8; ++j)
            *reinterpret_cast<unsigned short*>(Pb + (size_t)q * ROWB + (16 * j + cc) * 2) = f2bf(pr[j][jr]);
    }
    if (cc == 0) {
        #pragma unroll
        for (int jr = 0; jr < 4; ++jr) {
            const int q = 16 * w + 4 * g + jr;
            logits_ws[((size_t)b * HH + h) * SS + tks[q]] = lse[jr];
        }
    }
    // ---- write V phase 0 to Vt ----------------------------------------------
    {
        const float* fa = reinterpret_cast<const float*>(va);
        const float* fb = reinterpret_cast<const float*>(vbr);
        #pragma unroll
        for (int i = 0; i < 16; ++i) {
            const int dl = db * 16 + i;
            *reinterpret_cast<unsigned int*>(Vt + (size_t)dl * ROWB + kp * 4) = pk2bf(fa[i], fb[i]);
        }
    }
    // ---- prefetch V phase 1 (dims 64..127) into regs (T14 split) ------------
    #pragma unroll
    for (int i = 0; i < 4; ++i) {
        va[i]  = *reinterpret_cast<const float4*>(vra + 64 + i * 4);
        vbr[i] = *reinterpret_cast<const float4*>(vrb + 64 + i * 4);
    }
    __syncthreads();   // Pb + Vt(phase 0) visible

    // ---- PV -----------------------------------------------------------------
    short8_t pa[4];
    #pragma unroll
    for (int ks = 0; ks < 4; ++ks)
        pa[ks] = *reinterpret_cast<const short8_t*>(Pb + (size_t)(16 * w + cc) * ROWB + ks * 64 + g * 16);

    f32x4 oacc[8];
    __builtin_amdgcn_s_setprio(1);
    #pragma unroll
    for (int dt = 0; dt < 4; ++dt) {       // phase A: output dims 0..63
        oacc[dt] = (f32x4){0.f, 0.f, 0.f, 0.f};
        #pragma unroll
        for (int ks = 0; ks < 4; ++ks) {
            short8_t vb = *reinterpret_cast<const short8_t*>(Vt + (size_t)(16 * dt + cc) * ROWB + ks * 64 + g * 16);
            oacc[dt] = __builtin_amdgcn_mfma_f32_16x16x32_bf16(pa[ks], vb, oacc[dt], 0, 0, 0);
        }
    }
    __builtin_amdgcn_s_setprio(0);
    __syncthreads();   // phase-A reads of Vt done

    // ---- write V phase 1 to Vt ----------------------------------------------
    {
        const float* fa = reinterpret_cast<const float*>(va);
        const float* fb = reinterpret_cast<const float*>(vbr);
        #pragma unroll
        for (int i = 0; i < 16; ++i) {
            const int dl = db * 16 + i;
            *reinterpret_cast<unsigned int*>(Vt + (size_t)dl * ROWB + kp * 4) = pk2bf(fa[i], fb[i]);
        }
    }
    __syncthreads();

    __builtin_amdgcn_s_setprio(1);
    #pragma unroll
    for (int dt = 4; dt < 8; ++dt) {       // phase B: output dims 64..127
        oacc[dt] = (f32x4){0.f, 0.f, 0.f, 0.f};
        #pragma unroll
        for (int ks = 0; ks < 4; ++ks) {
            short8_t vb = *reinterpret_cast<const short8_t*>(Vt + (size_t)(16 * (dt - 4) + cc) * ROWB + ks * 64 + g * 16);
            oacc[dt] = __builtin_amdgcn_mfma_f32_16x16x32_bf16(pa[ks], vb, oacc[dt], 0, 0, 0);
        }
    }
    __builtin_amdgcn_s_setprio(0);

    // ---- scatter per-round outputs ------------------------------------------
    #pragma unroll
    for (int jr = 0; jr < 4; ++jr) {
        const int q = 16 * w + 4 * g + jr;
        const int t = tks[q];
        const size_t base = (((size_t)b * HH + h) * SS + t) * DD + cc;
        if (!obf16) {
            float* op = (float*)o_ws;
            #pragma unroll
            for (int dt = 0; dt < 8; ++dt) op[base + 16 * dt] = oacc[dt][jr];
        } else {
            unsigned short* op = (unsigned short*)o_ws;
            #pragma unroll
            for (int dt = 0; dt < 8; ++dt) op[base + 16 * dt] = f2bf(oacc[dt][jr]);
        }
    }
}

// ---------------- Kernel D: softmax-combine over hash rounds -----------------
__global__ __launch_bounds__(256) void combine_kernel(
    const float* __restrict__ logits_ws, const void* __restrict__ o_ws,
    float* __restrict__ outp, const int obf16)
{
    const int gid = blockIdx.x * 256 + threadIdx.x;
    const int row = gid >> 5;     // (b,t)
    const int seg = gid & 31;     // 4-float segment of D
    const int b = row >> 12;
    const int t = row & 4095;

    float l[8];
    float m = -3.0e38f;
    #pragma unroll
    for (int hh = 0; hh < 8; ++hh) {
        l[hh] = logits_ws[((size_t)b * HH + hh) * SS + t];
        m = fmaxf(m, l[hh]);
    }
    float ssum = 0.f;
    #pragma unroll
    for (int hh = 0; hh < 8; ++hh) { l[hh] = __expf(l[hh] - m); ssum += l[hh]; }
    const float inv = 1.0f / ssum;

    float a0 = 0.f, a1 = 0.f, a2 = 0.f, a3 = 0.f;
    #pragma unroll
    for (int hh = 0; hh < 8; ++hh) {
        const float wgt = l[hh] * inv;
        const size_t base = (((size_t)b * HH + hh) * SS + t) * DD + seg * 4;
        if (!obf16) {
            float4 ov = *reinterpret_cast<const float4*>((const float*)o_ws + base);
            a0 = fmaf(wgt, ov.x, a0); a1 = fmaf(wgt, ov.y, a1);
            a2 = fmaf(wgt, ov.z, a2); a3 = fmaf(wgt, ov.w, a3);
        } else {
            uint2 u = *reinterpret_cast<const uint2*>((const unsigned short*)o_ws + base);
            a0 = fmaf(wgt, bf2f((unsigned short)(u.x & 0xffffu)), a0);
            a1 = fmaf(wgt, bf2f((unsigned short)(u.x >> 16)), a1);
            a2 = fmaf(wgt, bf2f((unsigned short)(u.y & 0xffffu)), a2);
            a3 = fmaf(wgt, bf2f((unsigned short)(u.y >> 16)), a3);
        }
    }
    *reinterpret_cast<float4*>(outp + ((size_t)b * SS + t) * DD + seg * 4) =
        make_float4(a0, a1, a2, a3);
}

extern "C" void kernel_launch(void* const* d_in, const int* in_sizes, int n_in,
                              void* d_out, int out_size, void* d_ws, size_t ws_size,
                              hipStream_t stream) {
    const float* qk  = (const float*)d_in[0];
    const float* v   = (const float*)d_in[1];
    const float* rot = (const float*)d_in[2];

    float* out        = (float*)d_out;
    float* bucket_out = out + (size_t)BB * SS * DD;   // buckets written as f32

    char* ws = (char*)d_ws;
    int*            st        = (int*)ws;                              // 1,048,576 B
    unsigned char*  bucket_ws = (unsigned char*)(ws + 1048576);        //   262,144 B
    float*          logits_ws = (float*)(ws + 1048576 + 262144);       // 1,048,576 B
    void*           o_ws      = (void*)(ws + 2359296);                 // big scratch

    const int obf16 = 1;   // bf16 o-scratch: halves attn WRITE + combine read traffic

    hipLaunchKernelGGL(hash_kernel,    dim3(2048), dim3(256), 0, stream, qk, rot, bucket_ws, bucket_out);
    hipLaunchKernelGGL(sort_kernel,    dim3(64),   dim3(256), 0, stream, bucket_ws, st);
    hipLaunchKernelGGL(attn_kernel,    dim3(4096), dim3(256), 0, stream, qk, v, st, logits_ws, o_ws, obf16);
    hipLaunchKernelGGL(combine_kernel, dim3(4096), dim3(256), 0, stream, logits_ws, o_ws, out, obf16);
}

// Round 18
// 179.568 us; speedup vs baseline: 1.1485x; 1.0005x over previous
//
#include <hip/hip_runtime.h>
#include <hip/hip_bf16.h>

#define BB 8
#define SS 4096
#define DD 128
#define HH 8
#define NBUCK 64
#define CHUNKSZ 64
#define NCHUNK 512      // HH*SS/CHUNKSZ
#define HSTOT 32768     // HH*SS
#define ROWB 272        // bf16 tile row stride in bytes (128*2 + 16 pad)

typedef __attribute__((ext_vector_type(8))) short short8_t;   // 8 bf16 = 4 VGPR
typedef __attribute__((ext_vector_type(4))) float f32x4;

static __device__ __forceinline__ unsigned short f2bf(float f) {
    __hip_bfloat16 h = __float2bfloat16(f);
    return *reinterpret_cast<unsigned short*>(&h);
}
static __device__ __forceinline__ unsigned int pk2bf(float lo, float hi) {
    __hip_bfloat162 h = __float22bfloat162_rn(make_float2(lo, hi));   // v_cvt_pk_bf16_f32
    return *reinterpret_cast<unsigned int*>(&h);
}
static __device__ __forceinline__ float bf2f(unsigned short u) {
    return __uint_as_float(((unsigned int)u) << 16);
}

// ---------------- Kernel A: LSH hashing (register-resident) ------------------
// R9 structure + R12 XCD batch pinning (measured best: ~60us).
// R10 MFMA variant was slower (latency-bound); R13 reg-cache variant spilled.
// Bit-exactness-critical (buckets output): do not alter FMA order.
__global__ __launch_bounds__(256) void hash_kernel(
    const float* __restrict__ qk, const float* __restrict__ rot,
    unsigned char* __restrict__ bucket_ws, float* __restrict__ bucket_out)
{
    const int tid = threadIdx.x;
    const int bid = blockIdx.x;            // 0..2047 = tile(5) | h(3) | b(3)
    const int b   = bid & 7;               // XCD-pinned batch
    const int h   = (bid >> 3) & 7;
    const int t0  = (bid >> 6) * 128;
    const int tg  = tid >> 3;              // token group 0..31 (4 tokens each)
    const int jq  = tid & 7;               // j-quad 0..7 (4 columns each)

    const float* qbase = qk + ((size_t)b * SS + t0 + tg * 4) * DD;
    const float* rbase = rot + h * 32 + jq * 4;   // rot[f][h][j], f-stride 256

    float acc[4][4];
    #pragma unroll
    for (int r = 0; r < 4; ++r)
        #pragma unroll
        for (int j = 0; j < 4; ++j) acc[r][j] = 0.f;

    for (int c = 0; c < 16; ++c) {         // f in chunks of 8
        float4 qv[4][2];
        #pragma unroll
        for (int r = 0; r < 4; ++r) {
            qv[r][0] = *reinterpret_cast<const float4*>(qbase + r * DD + c * 8);
            qv[r][1] = *reinterpret_cast<const float4*>(qbase + r * DD + c * 8 + 4);
        }
        float4 rv[8];
        #pragma unroll
        for (int ff = 0; ff < 8; ++ff)
            rv[ff] = *reinterpret_cast<const float4*>(rbase + (size_t)(c * 8 + ff) * (HH * 32));
        #pragma unroll
        for (int ff = 0; ff < 8; ++ff) {
            #pragma unroll
            for (int r = 0; r < 4; ++r) {
                const float4 qh = qv[r][ff >> 2];
                const float qs = (ff & 2) ? ((ff & 1) ? qh.w : qh.z)
                                          : ((ff & 1) ? qh.y : qh.x);
                acc[r][0] = fmaf(qs, rv[ff].x, acc[r][0]);
                acc[r][1] = fmaf(qs, rv[ff].y, acc[r][1]);
                acc[r][2] = fmaf(qs, rv[ff].z, acc[r][2]);
                acc[r][3] = fmaf(qs, rv[ff].w, acc[r][3]);
            }
        }
    }

    const float TAU = 0.01f;
    #pragma unroll
    for (int r = 0; r < 4; ++r) {
        float bv = -3.0e38f; int bi = 0;
        #pragma unroll
        for (int j = 0; j < 4; ++j) {
            float v = acc[r][j];
            if (v > bv) { bv = v; bi = jq * 4 + j; }
        }
        #pragma unroll
        for (int j = 0; j < 4; ++j) {
            float v = -acc[r][j];
            if (v > bv) { bv = v; bi = 32 + jq * 4 + j; }
        }
        #pragma unroll
        for (int off = 1; off < 8; off <<= 1) {
            float ov = __shfl_xor(bv, off);
            int   oi = __shfl_xor(bi, off);
            if (ov > bv || (ov == bv && oi < bi)) { bv = ov; bi = oi; }
        }
        const float thrv = bv - TAU;
        int cnt = 0;
        #pragma unroll
        for (int j = 0; j < 4; ++j) {
            cnt += (acc[r][j]  > thrv) ? 1 : 0;
            cnt += (-acc[r][j] > thrv) ? 1 : 0;
        }
        #pragma unroll
        for (int off = 1; off < 8; off <<= 1) cnt += __shfl_xor(cnt, off);

        const int t = t0 + tg * 4 + r;
        if (cnt > 1) {
            const float* qrow = qk + ((size_t)b * SS + t) * DD;
            double bvd = -1.0e300; int bid2 = 64;
            #pragma unroll
            for (int j = 0; j < 4; ++j) {
                const bool fp = (acc[r][j] > thrv);
                const bool fn = (-acc[r][j] > thrv);
                if (fp || fn) {
                    const float* rcol = rot + h * 32 + jq * 4 + j;
                    double a = 0.0;
                    for (int f = 0; f < DD; ++f)
                        a = fma((double)qrow[f], (double)rcol[(size_t)f * (HH * 32)], a);
                    if (fp &&  a > bvd)                         { bvd = a;  bid2 = jq * 4 + j; }
                    if (fn && (-a > bvd ||
                               (-a == bvd && 32 + jq * 4 + j < bid2))) { bvd = -a; bid2 = 32 + jq * 4 + j; }
                }
            }
            #pragma unroll
            for (int off = 1; off < 8; off <<= 1) {
                double ov = __shfl_xor(bvd, off);
                int    oi = __shfl_xor(bid2, off);
                if (ov > bvd || (ov == bvd && oi < bid2)) { bvd = ov; bid2 = oi; }
            }
            bi = bid2;
        }
        if (jq == 0) {
            const size_t o = ((size_t)b * HH + h) * SS + t;
            bucket_ws[o]  = (unsigned char)bi;
            bucket_out[o] = (float)(bi + h * NBUCK);
        }
    }
}

// ---------------- Kernel B: stable counting sort per (b,h) -------------------
__global__ __launch_bounds__(256) void sort_kernel(
    const unsigned char* __restrict__ bucket_ws, int* __restrict__ st)
{
    __shared__ unsigned int hist[256 * 65];   // padded stride 65
    __shared__ unsigned int totals[64];
    const int tid = threadIdx.x;
    const int bh  = blockIdx.x;               // 0..63 = b*8+h

    unsigned int* hrow = &hist[tid * 65];
    #pragma unroll
    for (int j = 0; j < 65; ++j) hrow[j] = 0u;

    const uint4 raw = *reinterpret_cast<const uint4*>(bucket_ws + (size_t)bh * SS + tid * 16);
    unsigned int w[4] = {raw.x, raw.y, raw.z, raw.w};

    #pragma unroll
    for (int c = 0; c < 16; ++c) {
        unsigned int bk = (w[c >> 2] >> ((c & 3) * 8)) & 255u;
        hrow[bk] += 1u;
    }
    __syncthreads();

    if (tid < 64) {
        unsigned int run = 0;
        for (int c2 = 0; c2 < 256; ++c2) {
            unsigned int x = hist[c2 * 65 + tid];
            hist[c2 * 65 + tid] = run;
            run += x;
        }
        totals[tid] = run;
    }
    __syncthreads();
    if (tid == 0) {
        unsigned int base = 0;
        for (int k = 0; k < 64; ++k) { unsigned int x = totals[k]; totals[k] = base; base += x; }
    }
    __syncthreads();

    int* dst = st + (size_t)bh * SS;
    #pragma unroll
    for (int c = 0; c < 16; ++c) {
        unsigned int bk = (w[c >> 2] >> ((c & 3) * 8)) & 255u;
        unsigned int pos = totals[bk] + hrow[bk];
        hrow[bk] += 1u;
        dst[pos] = tid * 16 + c;
    }
}

// ---------------- Kernel C: chunked attention via bf16 MFMA ------------------
// R12 structure: LDS -> 4 blocks/CU, XCD batch pinning, setprio (T5),
// V in two 64-dim phases with early prefetch (T14), fast exp/log (R15).
// R16: ninv via adjacent-lane shfl (halves of row r live in lanes 2r,2r+1)
// written directly during K-stage -- deletes the psums pass and one barrier
// (6 -> 5 serial phases). LDS 36864 -> 35840.
__global__ __launch_bounds__(256, 4) void attn_kernel(
    const float* __restrict__ qk, const float* __restrict__ vv,
    const int* __restrict__ st, float* __restrict__ logits_ws,
    void* __restrict__ o_ws, const int obf16)
{
    __shared__ __align__(16) char smem[35840];
    char*  Kb    = smem;
    char*  Pb    = smem;                       // after Kb retired
    char*  Vt    = smem + 17408;               // 64 dim-rows x 272 B
    int*   tks   = (int*)(smem + 34816);
    float* ninv  = (float*)(smem + 35328);

    const int tid = threadIdx.x;
    const int bc  = blockIdx.x;
    const int b   = bc & 7;                    // XCD-pinned batch
    const int c   = bc >> 3;                   // chunk 0..511
    const int h   = c >> 6;
    const int cprev = (c == 0) ? (NCHUNK - 1) : (c - 1);
    const int* stb  = st + (size_t)b * HSTOT;

    // ---- V phase-0 prefetch: issue FIRST (T14) ------------------------------
    const int kp = tid & 63;                   // token pair 2kp, 2kp+1
    const int db = tid >> 6;                   // dim sub-block (16 dims)
    const int idxa = 2 * kp, idxb = 2 * kp + 1;
    const int tva = stb[(size_t)((idxa < 64) ? c : cprev) * CHUNKSZ + (idxa & 63)];
    const int tvb = stb[(size_t)((idxb < 64) ? c : cprev) * CHUNKSZ + (idxb & 63)];
    const float* vra = vv + ((size_t)b * SS + tva) * DD + db * 16;
    const float* vrb = vv + ((size_t)b * SS + tvb) * DD + db * 16;
    float4 va[4], vbr[4];
    #pragma unroll
    for (int i = 0; i < 4; ++i) {
        va[i]  = *reinterpret_cast<const float4*>(vra + i * 4);
        vbr[i] = *reinterpret_cast<const float4*>(vrb + i * 4);
    }

    // own K-row index straight from global (L2-hot) -- off the barrier path
    const int rowk  = tid >> 1, halfk = tid & 1;
    const int t_mine = stb[(size_t)((rowk < 64) ? c : cprev) * CHUNKSZ + (rowk & 63)];

    if (tid < 128) {                           // LDS copy for later phases
        tks[tid] = stb[(size_t)((tid < 64) ? c : cprev) * CHUNKSZ + (tid & 63)];
    }

    // ---- stage K (raw qk rows, bf16) + ninv via lane-pair shfl --------------
    {
        const float* srow = qk + ((size_t)b * SS + t_mine) * DD + halfk * 64;
        char* krow = Kb + (size_t)rowk * ROWB + halfk * 128;
        float ss = 0.f;
        #pragma unroll
        for (int i = 0; i < 8; ++i) {
            float4 v0 = *reinterpret_cast<const float4*>(srow + i * 8);
            float4 v1 = *reinterpret_cast<const float4*>(srow + i * 8 + 4);
            ss = fmaf(v0.x, v0.x, ss); ss = fmaf(v0.y, v0.y, ss);
            ss = fmaf(v0.z, v0.z, ss); ss = fmaf(v0.w, v0.w, ss);
            ss = fmaf(v1.x, v1.x, ss); ss = fmaf(v1.y, v1.y, ss);
            ss = fmaf(v1.z, v1.z, ss); ss = fmaf(v1.w, v1.w, ss);
            uint4 pk;
            pk.x = pk2bf(v0.x, v0.y); pk.y = pk2bf(v0.z, v0.w);
            pk.z = pk2bf(v1.x, v1.y); pk.w = pk2bf(v1.z, v1.w);
            *reinterpret_cast<uint4*>(krow + i * 16) = pk;
        }
        // halves of row rowk are in adjacent lanes 2*rowk, 2*rowk+1
        const float other = __shfl_xor(ss, 1);
        if (halfk == 0)    // (half0)+(half1): same order as old psums[2t]+psums[2t+1]
            ninv[rowk] = rsqrtf(ss + other + 1e-6f) * 0.088388347648318447f;
    }
    __syncthreads();   // single barrier: K tile + ninv + tks all visible

    const int w  = tid >> 6;     // wave id: q-tile rows 16w..16w+15
    const int ln = tid & 63;
    const int cc = ln & 15;      // fragment col lane
    const int g  = ln >> 4;      // fragment k-group / row-group

    // ---- QK^T ---------------------------------------------------------------
    short8_t aq[4];
    #pragma unroll
    for (int ks = 0; ks < 4; ++ks)
        aq[ks] = *reinterpret_cast<const short8_t*>(Kb + (size_t)(16 * w + cc) * ROWB + ks * 64 + g * 16);

    f32x4 acc[8];
    __builtin_amdgcn_s_setprio(1);
    #pragma unroll
    for (int j = 0; j < 8; ++j) {
        acc[j] = (f32x4){0.f, 0.f, 0.f, 0.f};
        #pragma unroll
        for (int ks = 0; ks < 4; ++ks) {
            short8_t bk = *reinterpret_cast<const short8_t*>(Kb + (size_t)(16 * j + cc) * ROWB + ks * 64 + g * 16);
            acc[j] = __builtin_amdgcn_mfma_f32_16x16x32_bf16(aq[ks], bk, acc[j], 0, 0, 0);
        }
    }
    __builtin_amdgcn_s_setprio(0);

    // ---- softmax (regs, fast-math exp/log) ----------------------------------
    float lse[4];
    float pr[8][4];
    #pragma unroll
    for (int jr = 0; jr < 4; ++jr) {
        const int q  = 16 * w + 4 * g + jr;
        const int tq = tks[q];
        float m = -3.0e38f;
        #pragma unroll
        for (int j = 0; j < 8; ++j) {
            const int k = 16 * j + cc;
            float val = acc[j][jr] * ninv[k];
            if (tks[k] == tq) val = -1e5f;
            pr[j][jr] = val;
            m = fmaxf(m, val);
        }
        #pragma unroll
        for (int off = 1; off < 16; off <<= 1) m = fmaxf(m, __shfl_xor(m, off));
        float ssum = 0.f;
        #pragma unroll
        for (int j = 0; j < 8; ++j) { float ex = __expf(pr[j][jr] - m); pr[j][jr] = ex; ssum += ex; }
        #pragma unroll
        for (int off = 1; off < 16; off <<= 1) ssum += __shfl_xor(ssum, off);
        const float inv = 1.0f / ssum;
        #pragma unroll
        for (int j = 0; j < 8; ++j) pr[j][jr] *= inv;
        lse[jr] = m + __logf(ssum);
    }

    __syncthreads();   // all waves done reading Kb; Pb/Vt may be written

    // ---- write P (bf16) -----------------------------------------------------
    #pragma unroll
    for (int jr = 0; jr < 4; ++jr) {
        const int q = 16 * w + 4 * g + jr;
        #pragma unroll
        for (int j = 0; j < 8; ++j)
            *reinterpret_cast<unsigned short*>(Pb + (size_t)q * ROWB + (16 * j + cc) * 2) = f2bf(pr[j][jr]);
    }
    if (cc == 0) {
        #pragma unroll
        for (int jr = 0; jr < 4; ++jr) {
            const int q = 16 * w + 4 * g + jr;
            logits_ws[((size_t)b * HH + h) * SS + tks[q]] = lse[jr];
        }
    }
    // ---- write V phase 0 to Vt ----------------------------------------------
    {
        const float* fa = reinterpret_cast<const float*>(va);
        const float* fb = reinterpret_cast<const float*>(vbr);
        #pragma unroll
        for (int i = 0; i < 16; ++i) {
            const int dl = db * 16 + i;
            *reinterpret_cast<unsigned int*>(Vt + (size_t)dl * ROWB + kp * 4) = pk2bf(fa[i], fb[i]);
        }
    }
    // ---- prefetch V phase 1 (dims 64..127) into regs (T14 split) ------------
    #pragma unroll
    for (int i = 0; i < 4; ++i) {
        va[i]  = *reinterpret_cast<const float4*>(vra + 64 + i * 4);
        vbr[i] = *reinterpret_cast<const float4*>(vrb + 64 + i * 4);
    }
    __syncthreads();   // Pb + Vt(phase 0) visible

    // ---- PV -----------------------------------------------------------------
    short8_t pa[4];
    #pragma unroll
    for (int ks = 0; ks < 4; ++ks)
        pa[ks] = *reinterpret_cast<const short8_t*>(Pb + (size_t)(16 * w + cc) * ROWB + ks * 64 + g * 16);

    f32x4 oacc[8];
    __builtin_amdgcn_s_setprio(1);
    #pragma unroll
    for (int dt = 0; dt < 4; ++dt) {       // phase A: output dims 0..63
        oacc[dt] = (f32x4){0.f, 0.f, 0.f, 0.f};
        #pragma unroll
        for (int ks = 0; ks < 4; ++ks) {
            short8_t vb = *reinterpret_cast<const short8_t*>(Vt + (size_t)(16 * dt + cc) * ROWB + ks * 64 + g * 16);
            oacc[dt] = __builtin_amdgcn_mfma_f32_16x16x32_bf16(pa[ks], vb, oacc[dt], 0, 0, 0);
        }
    }
    __builtin_amdgcn_s_setprio(0);
    __syncthreads();   // phase-A reads of Vt done

    // ---- write V phase 1 to Vt ----------------------------------------------
    {
        const float* fa = reinterpret_cast<const float*>(va);
        const float* fb = reinterpret_cast<const float*>(vbr);
        #pragma unroll
        for (int i = 0; i < 16; ++i) {
            const int dl = db * 16 + i;
            *reinterpret_cast<unsigned int*>(Vt + (size_t)dl * ROWB + kp * 4) = pk2bf(fa[i], fb[i]);
        }
    }
    __syncthreads();

    __builtin_amdgcn_s_setprio(1);
    #pragma unroll
    for (int dt = 4; dt < 8; ++dt) {       // phase B: output dims 64..127
        oacc[dt] = (f32x4){0.f, 0.f, 0.f, 0.f};
        #pragma unroll
        for (int ks = 0; ks < 4; ++ks) {
            short8_t vb = *reinterpret_cast<const short8_t*>(Vt + (size_t)(16 * (dt - 4) + cc) * ROWB + ks * 64 + g * 16);
            oacc[dt] = __builtin_amdgcn_mfma_f32_16x16x32_bf16(pa[ks], vb, oacc[dt], 0, 0, 0);
        }
    }
    __builtin_amdgcn_s_setprio(0);

    // ---- scatter per-round outputs ------------------------------------------
    #pragma unroll
    for (int jr = 0; jr < 4; ++jr) {
        const int q = 16 * w + 4 * g + jr;
        const int t = tks[q];
        const size_t base = (((size_t)b * HH + h) * SS + t) * DD + cc;
        if (!obf16) {
            float* op = (float*)o_ws;
            #pragma unroll
            for (int dt = 0; dt < 8; ++dt) op[base + 16 * dt] = oacc[dt][jr];
        } else {
            unsigned short* op = (unsigned short*)o_ws;
            #pragma unroll
            for (int dt = 0; dt < 8; ++dt) op[base + 16 * dt] = f2bf(oacc[dt][jr]);
        }
    }
}

// ---------------- Kernel D: softmax-combine over hash rounds -----------------
__global__ __launch_bounds__(256) void combine_kernel(
    const float* __restrict__ logits_ws, const void* __restrict__ o_ws,
    float* __restrict__ outp, const int obf16)
{
    const int gid = blockIdx.x * 256 + threadIdx.x;
    const int row = gid >> 5;     // (b,t)
    const int seg = gid & 31;     // 4-float segment of D
    const int b = row >> 12;
    const int t = row & 4095;

    float l[8];
    float m = -3.0e38f;
    #pragma unroll
    for (int hh = 0; hh < 8; ++hh) {
        l[hh] = logits_ws[((size_t)b * HH + hh) * SS + t];
        m = fmaxf(m, l[hh]);
    }
    float ssum = 0.f;
    #pragma unroll
    for (int hh = 0; hh < 8; ++hh) { l[hh] = __expf(l[hh] - m); ssum += l[hh]; }
    const float inv = 1.0f / ssum;

    float a0 = 0.f, a1 = 0.f, a2 = 0.f, a3 = 0.f;
    #pragma unroll
    for (int hh = 0; hh < 8; ++hh) {
        const float wgt = l[hh] * inv;
        const size_t base = (((size_t)b * HH + hh) * SS + t) * DD + seg * 4;
        if (!obf16) {
            float4 ov = *reinterpret_cast<const float4*>((const float*)o_ws + base);
            a0 = fmaf(wgt, ov.x, a0); a1 = fmaf(wgt, ov.y, a1);
            a2 = fmaf(wgt, ov.z, a2); a3 = fmaf(wgt, ov.w, a3);
        } else {
            uint2 u = *reinterpret_cast<const uint2*>((const unsigned short*)o_ws + base);
            a0 = fmaf(wgt, bf2f((unsigned short)(u.x & 0xffffu)), a0);
            a1 = fmaf(wgt, bf2f((unsigned short)(u.x >> 16)), a1);
            a2 = fmaf(wgt, bf2f((unsigned short)(u.y & 0xffffu)), a2);
            a3 = fmaf(wgt, bf2f((unsigned short)(u.y >> 16)), a3);
        }
    }
    *reinterpret_cast<float4*>(outp + ((size_t)b * SS + t) * DD + seg * 4) =
        make_float4(a0, a1, a2, a3);
}

extern "C" void kernel_launch(void* const* d_in, const int* in_sizes, int n_in,
                              void* d_out, int out_size, void* d_ws, size_t ws_size,
                              hipStream_t stream) {
    const float* qk  = (const float*)d_in[0];
    const float* v   = (const float*)d_in[1];
    const float* rot = (const float*)d_in[2];

    float* out        = (float*)d_out;
    float* bucket_out = out + (size_t)BB * SS * DD;   // buckets written as f32

    char* ws = (char*)d_ws;
    int*            st        = (int*)ws;                              // 1,048,576 B
    unsigned char*  bucket_ws = (unsigned char*)(ws + 1048576);        //   262,144 B
    float*          logits_ws = (float*)(ws + 1048576 + 262144);       // 1,048,576 B
    void*           o_ws      = (void*)(ws + 2359296);                 // big scratch

    const int obf16 = 1;   // bf16 o-scratch: halves attn WRITE + combine read traffic

    hipLaunchKernelGGL(hash_kernel,    dim3(2048), dim3(256), 0, stream, qk, rot, bucket_ws, bucket_out);
    hipLaunchKernelGGL(sort_kernel,    dim3(64),   dim3(256), 0, stream, bucket_ws, st);
    hipLaunchKernelGGL(attn_kernel,    dim3(4096), dim3(256), 0, stream, qk, v, st, logits_ws, o_ws, obf16);
    hipLaunchKernelGGL(combine_kernel, dim3(4096), dim3(256), 0, stream, logits_ws, o_ws, out, obf16);
}

// Round 19
// 154.597 us; speedup vs baseline: 1.3340x; 1.1615x over previous
//
#include <hip/hip_runtime.h>
#include <hip/hip_bf16.h>

#define BB 8
#define SS 4096
#define DD 128
#define HH 8
#define NBUCK 64
#define CHUNKSZ 64
#define NCHUNK 512      // HH*SS/CHUNKSZ
#define HSTOT 32768     // HH*SS
#define ROWB 272        // bf16 tile row stride in bytes (128*2 + 16 pad)

typedef __attribute__((ext_vector_type(8))) short short8_t;   // 8 bf16 = 4 VGPR
typedef __attribute__((ext_vector_type(4))) float f32x4;

static __device__ __forceinline__ unsigned short f2bf(float f) {
    __hip_bfloat16 h = __float2bfloat16(f);
    return *reinterpret_cast<unsigned short*>(&h);
}
static __device__ __forceinline__ unsigned int pk2bf(float lo, float hi) {
    __hip_bfloat162 h = __float22bfloat162_rn(make_float2(lo, hi));   // v_cvt_pk_bf16_f32
    return *reinterpret_cast<unsigned int*>(&h);
}
static __device__ __forceinline__ float bf2f(unsigned short u) {
    return __uint_as_float(((unsigned int)u) << 16);
}

// ---------------- Kernel A: LSH hashing (register-resident) ------------------
// R9 structure + R12 XCD batch pinning. R19: the block's rot slice (128 f x
// 32 cols for its h-round, 16KB f32) is staged ONCE into LDS -- rot loads were
// L1-thrashing L2 round-trips (128KB footprint vs 32KB L1) and 2/3 of VMEM
// issue. LDS reads are conflict-free (8 distinct 16B addrs x 8-way broadcast
// per wave). FMA order unchanged; f64 fallback still reads global rot ->
// buckets bit-identical. 16KB LDS x 8 blocks/CU keeps max-wave TLP.
__global__ __launch_bounds__(256) void hash_kernel(
    const float* __restrict__ qk, const float* __restrict__ rot,
    unsigned char* __restrict__ bucket_ws, float* __restrict__ bucket_out)
{
    __shared__ float rotس[128 * 32];
    const int tid = threadIdx.x;
    const int bid = blockIdx.x;            // 0..2047 = tile(5) | h(3) | b(3)
    const int b   = bid & 7;               // XCD-pinned batch
    const int h   = (bid >> 3) & 7;
    const int t0  = (bid >> 6) * 128;
    const int tg  = tid >> 3;              // token group 0..31 (4 tokens each)
    const int jq  = tid & 7;               // j-quad 0..7 (4 columns each)

    // ---- stage rot[f][h*32 .. h*32+31] -> rots[f][0..31] (16KB, once) -------
    {
        const int row = tid >> 1, half16 = tid & 1;   // 128 rows x 2 halves
        const float* src = rot + (size_t)row * 256 + h * 32 + half16 * 16;
        float* dst = &rotس[row * 32 + half16 * 16];
        #pragma unroll
        for (int i = 0; i < 4; ++i)
            *reinterpret_cast<float4*>(dst + i * 4) =
                *reinterpret_cast<const float4*>(src + i * 4);
    }
    __syncthreads();

    const float* qbase = qk + ((size_t)b * SS + t0 + tg * 4) * DD;

    float acc[4][4];
    #pragma unroll
    for (int r = 0; r < 4; ++r)
        #pragma unroll
        for (int j = 0; j < 4; ++j) acc[r][j] = 0.f;

    for (int c = 0; c < 16; ++c) {         // f in chunks of 8
        float4 qv[4][2];
        #pragma unroll
        for (int r = 0; r < 4; ++r) {
            qv[r][0] = *reinterpret_cast<const float4*>(qbase + r * DD + c * 8);
            qv[r][1] = *reinterpret_cast<const float4*>(qbase + r * DD + c * 8 + 4);
        }
        float4 rv[8];
        #pragma unroll
        for (int ff = 0; ff < 8; ++ff)
            rv[ff] = *reinterpret_cast<const float4*>(&rotس[(c * 8 + ff) * 32 + jq * 4]);
        #pragma unroll
        for (int ff = 0; ff < 8; ++ff) {
            #pragma unroll
            for (int r = 0; r < 4; ++r) {
                const float4 qh = qv[r][ff >> 2];
                const float qs = (ff & 2) ? ((ff & 1) ? qh.w : qh.z)
                                          : ((ff & 1) ? qh.y : qh.x);
                acc[r][0] = fmaf(qs, rv[ff].x, acc[r][0]);
                acc[r][1] = fmaf(qs, rv[ff].y, acc[r][1]);
                acc[r][2] = fmaf(qs, rv[ff].z, acc[r][2]);
                acc[r][3] = fmaf(qs, rv[ff].w, acc[r][3]);
            }
        }
    }

    const float TAU = 0.01f;
    #pragma unroll
    for (int r = 0; r < 4; ++r) {
        float bv = -3.0e38f; int bi = 0;
        #pragma unroll
        for (int j = 0; j < 4; ++j) {
            float v = acc[r][j];
            if (v > bv) { bv = v; bi = jq * 4 + j; }
        }
        #pragma unroll
        for (int j = 0; j < 4; ++j) {
            float v = -acc[r][j];
            if (v > bv) { bv = v; bi = 32 + jq * 4 + j; }
        }
        #pragma unroll
        for (int off = 1; off < 8; off <<= 1) {
            float ov = __shfl_xor(bv, off);
            int   oi = __shfl_xor(bi, off);
            if (ov > bv || (ov == bv && oi < bi)) { bv = ov; bi = oi; }
        }
        const float thrv = bv - TAU;
        int cnt = 0;
        #pragma unroll
        for (int j = 0; j < 4; ++j) {
            cnt += (acc[r][j]  > thrv) ? 1 : 0;
            cnt += (-acc[r][j] > thrv) ? 1 : 0;
        }
        #pragma unroll
        for (int off = 1; off < 8; off <<= 1) cnt += __shfl_xor(cnt, off);

        const int t = t0 + tg * 4 + r;
        if (cnt > 1) {
            const float* qrow = qk + ((size_t)b * SS + t) * DD;
            double bvd = -1.0e300; int bid2 = 64;
            #pragma unroll
            for (int j = 0; j < 4; ++j) {
                const bool fp = (acc[r][j] > thrv);
                const bool fn = (-acc[r][j] > thrv);
                if (fp || fn) {
                    const float* rcol = rot + h * 32 + jq * 4 + j;
                    double a = 0.0;
                    for (int f = 0; f < DD; ++f)
                        a = fma((double)qrow[f], (double)rcol[(size_t)f * (HH * 32)], a);
                    if (fp &&  a > bvd)                         { bvd = a;  bid2 = jq * 4 + j; }
                    if (fn && (-a > bvd ||
                               (-a == bvd && 32 + jq * 4 + j < bid2))) { bvd = -a; bid2 = 32 + jq * 4 + j; }
                }
            }
            #pragma unroll
            for (int off = 1; off < 8; off <<= 1) {
                double ov = __shfl_xor(bvd, off);
                int    oi = __shfl_xor(bid2, off);
                if (ov > bvd || (ov == bvd && oi < bid2)) { bvd = ov; bid2 = oi; }
            }
            bi = bid2;
        }
        if (jq == 0) {
            const size_t o = ((size_t)b * HH + h) * SS + t;
            bucket_ws[o]  = (unsigned char)bi;
            bucket_out[o] = (float)(bi + h * NBUCK);
        }
    }
}

// ---------------- Kernel B: stable counting sort per (b,h) -------------------
__global__ __launch_bounds__(256) void sort_kernel(
    const unsigned char* __restrict__ bucket_ws, int* __restrict__ st)
{
    __shared__ unsigned int hist[256 * 65];   // padded stride 65
    __shared__ unsigned int totals[64];
    const int tid = threadIdx.x;
    const int bh  = blockIdx.x;               // 0..63 = b*8+h

    unsigned int* hrow = &hist[tid * 65];
    #pragma unroll
    for (int j = 0; j < 65; ++j) hrow[j] = 0u;

    const uint4 raw = *reinterpret_cast<const uint4*>(bucket_ws + (size_t)bh * SS + tid * 16);
    unsigned int w[4] = {raw.x, raw.y, raw.z, raw.w};

    #pragma unroll
    for (int c = 0; c < 16; ++c) {
        unsigned int bk = (w[c >> 2] >> ((c & 3) * 8)) & 255u;
        hrow[bk] += 1u;
    }
    __syncthreads();

    if (tid < 64) {
        unsigned int run = 0;
        for (int c2 = 0; c2 < 256; ++c2) {
            unsigned int x = hist[c2 * 65 + tid];
            hist[c2 * 65 + tid] = run;
            run += x;
        }
        totals[tid] = run;
    }
    __syncthreads();
    if (tid == 0) {
        unsigned int base = 0;
        for (int k = 0; k < 64; ++k) { unsigned int x = totals[k]; totals[k] = base; base += x; }
    }
    __syncthreads();

    int* dst = st + (size_t)bh * SS;
    #pragma unroll
    for (int c = 0; c < 16; ++c) {
        unsigned int bk = (w[c >> 2] >> ((c & 3) * 8)) & 255u;
        unsigned int pos = totals[bk] + hrow[bk];
        hrow[bk] += 1u;
        dst[pos] = tid * 16 + c;
    }
}

// ---------------- Kernel C: chunked attention via bf16 MFMA ------------------
// R12 structure: LDS -> 4 blocks/CU, XCD batch pinning, setprio (T5),
// V in two 64-dim phases with early prefetch (T14), fast exp/log (R15),
// ninv via lane-pair shfl during K-stage (R16; 5 barriers). Measured ~93us,
// latency-bound (MfmaUtil 7 / VALU 29 / Occ 39) -- four structural attempts
// (R13 occupancy, R14 prefetch, R16 barrier, T5) all neutral; do not churn.
__global__ __launch_bounds__(256, 4) void attn_kernel(
    const float* __restrict__ qk, const float* __restrict__ vv,
    const int* __restrict__ st, float* __restrict__ logits_ws,
    void* __restrict__ o_ws, const int obf16)
{
    __shared__ __align__(16) char smem[35840];
    char*  Kb    = smem;
    char*  Pb    = smem;                       // after Kb retired
    char*  Vt    = smem + 17408;               // 64 dim-rows x 272 B
    int*   tks   = (int*)(smem + 34816);
    float* ninv  = (float*)(smem + 35328);

    const int tid = threadIdx.x;
    const int bc  = blockIdx.x;
    const int b   = bc & 7;                    // XCD-pinned batch
    const int c   = bc >> 3;                   // chunk 0..511
    const int h   = c >> 6;
    const int cprev = (c == 0) ? (NCHUNK - 1) : (c - 1);
    const int* stb  = st + (size_t)b * HSTOT;

    // ---- V phase-0 prefetch: issue FIRST (T14) ------------------------------
    const int kp = tid & 63;                   // token pair 2kp, 2kp+1
    const int db = tid >> 6;                   // dim sub-block (16 dims)
    const int idxa = 2 * kp, idxb = 2 * kp + 1;
    const int tva = stb[(size_t)((idxa < 64) ? c : cprev) * CHUNKSZ + (idxa & 63)];
    const int tvb = stb[(size_t)((idxb < 64) ? c : cprev) * CHUNKSZ + (idxb & 63)];
    const float* vra = vv + ((size_t)b * SS + tva) * DD + db * 16;
    const float* vrb = vv + ((size_t)b * SS + tvb) * DD + db * 16;
    float4 va[4], vbr[4];
    #pragma unroll
    for (int i = 0; i < 4; ++i) {
        va[i]  = *reinterpret_cast<const float4*>(vra + i * 4);
        vbr[i] = *reinterpret_cast<const float4*>(vrb + i * 4);
    }

    // own K-row index straight from global (L2-hot) -- off the barrier path
    const int rowk  = tid >> 1, halfk = tid & 1;
    const int t_mine = stb[(size_t)((rowk < 64) ? c : cprev) * CHUNKSZ + (rowk & 63)];

    if (tid < 128) {                           // LDS copy for later phases
        tks[tid] = stb[(size_t)((tid < 64) ? c : cprev) * CHUNKSZ + (tid & 63)];
    }

    // ---- stage K (raw qk rows, bf16) + ninv via lane-pair shfl --------------
    {
        const float* srow = qk + ((size_t)b * SS + t_mine) * DD + halfk * 64;
        char* krow = Kb + (size_t)rowk * ROWB + halfk * 128;
        float ss = 0.f;
        #pragma unroll
        for (int i = 0; i < 8; ++i) {
            float4 v0 = *reinterpret_cast<const float4*>(srow + i * 8);
            float4 v1 = *reinterpret_cast<const float4*>(srow + i * 8 + 4);
            ss = fmaf(v0.x, v0.x, ss); ss = fmaf(v0.y, v0.y, ss);
            ss = fmaf(v0.z, v0.z, ss); ss = fmaf(v0.w, v0.w, ss);
            ss = fmaf(v1.x, v1.x, ss); ss = fmaf(v1.y, v1.y, ss);
            ss = fmaf(v1.z, v1.z, ss); ss = fmaf(v1.w, v1.w, ss);
            uint4 pk;
            pk.x = pk2bf(v0.x, v0.y); pk.y = pk2bf(v0.z, v0.w);
            pk.z = pk2bf(v1.x, v1.y); pk.w = pk2bf(v1.z, v1.w);
            *reinterpret_cast<uint4*>(krow + i * 16) = pk;
        }
        // halves of row rowk are in adjacent lanes 2*rowk, 2*rowk+1
        const float other = __shfl_xor(ss, 1);
        if (halfk == 0)    // (half0)+(half1): same order as old psums[2t]+psums[2t+1]
            ninv[rowk] = rsqrtf(ss + other + 1e-6f) * 0.088388347648318447f;
    }
    __syncthreads();   // single barrier: K tile + ninv + tks all visible

    const int w  = tid >> 6;     // wave id: q-tile rows 16w..16w+15
    const int ln = tid & 63;
    const int cc = ln & 15;      // fragment col lane
    const int g  = ln >> 4;      // fragment k-group / row-group

    // ---- QK^T ---------------------------------------------------------------
    short8_t aq[4];
    #pragma unroll
    for (int ks = 0; ks < 4; ++ks)
        aq[ks] = *reinterpret_cast<const short8_t*>(Kb + (size_t)(16 * w + cc) * ROWB + ks * 64 + g * 16);

    f32x4 acc[8];
    __builtin_amdgcn_s_setprio(1);
    #pragma unroll
    for (int j = 0; j < 8; ++j) {
        acc[j] = (f32x4){0.f, 0.f, 0.f, 0.f};
        #pragma unroll
        for (int ks = 0; ks < 4; ++ks) {
            short8_t bk = *reinterpret_cast<const short8_t*>(Kb + (size_t)(16 * j + cc) * ROWB + ks * 64 + g * 16);
            acc[j] = __builtin_amdgcn_mfma_f32_16x16x32_bf16(aq[ks], bk, acc[j], 0, 0, 0);
        }
    }
    __builtin_amdgcn_s_setprio(0);

    // ---- softmax (regs, fast-math exp/log) ----------------------------------
    float lse[4];
    float pr[8][4];
    #pragma unroll
    for (int jr = 0; jr < 4; ++jr) {
        const int q  = 16 * w + 4 * g + jr;
        const int tq = tks[q];
        float m = -3.0e38f;
        #pragma unroll
        for (int j = 0; j < 8; ++j) {
            const int k = 16 * j + cc;
            float val = acc[j][jr] * ninv[k];
            if (tks[k] == tq) val = -1e5f;
            pr[j][jr] = val;
            m = fmaxf(m, val);
        }
        #pragma unroll
        for (int off = 1; off < 16; off <<= 1) m = fmaxf(m, __shfl_xor(m, off));
        float ssum = 0.f;
        #pragma unroll
        for (int j = 0; j < 8; ++j) { float ex = __expf(pr[j][jr] - m); pr[j][jr] = ex; ssum += ex; }
        #pragma unroll
        for (int off = 1; off < 16; off <<= 1) ssum += __shfl_xor(ssum, off);
        const float inv = 1.0f / ssum;
        #pragma unroll
        for (int j = 0; j < 8; ++j) pr[j][jr] *= inv;
        lse[jr] = m + __logf(ssum);
    }

    __syncthreads();   // all waves done reading Kb; Pb/Vt may be written

    // ---- write P (bf16) -----------------------------------------------------
    #pragma unroll
    for (int jr = 0; jr < 4; ++jr) {
        const int q = 16 * w + 4 * g + jr;
        #pragma unroll
        for (int j = 0; j < 8; ++j)
            *reinterpret_cast<unsigned short*>(Pb + (size_t)q * ROWB + (16 * j + cc) * 2) = f2bf(pr[j][jr]);
    }
    if (cc == 0) {
        #pragma unroll
        for (int jr = 0; jr < 4; ++jr) {
            const int q = 16 * w + 4 * g + jr;
            logits_ws[((size_t)b * HH + h) * SS + tks[q]] = lse[jr];
        }
    }
    // ---- write V phase 0 to Vt ----------------------------------------------
    {
        const float* fa = reinterpret_cast<const float*>(va);
        const float* fb = reinterpret_cast<const float*>(vbr);
        #pragma unroll
        for (int i = 0; i < 16; ++i) {
            const int dl = db * 16 + i;
            *reinterpret_cast<unsigned int*>(Vt + (size_t)dl * ROWB + kp * 4) = pk2bf(fa[i], fb[i]);
        }
    }
    // ---- prefetch V phase 1 (dims 64..127) into regs (T14 split) ------------
    #pragma unroll
    for (int i = 0; i < 4; ++i) {
        va[i]  = *reinterpret_cast<const float4*>(vra + 64 + i * 4);
        vbr[i] = *reinterpret_cast<const float4*>(vrb + 64 + i * 4);
    }
    __syncthreads();   // Pb + Vt(phase 0) visible

    // ---- PV -----------------------------------------------------------------
    short8_t pa[4];
    #pragma unroll
    for (int ks = 0; ks < 4; ++ks)
        pa[ks] = *reinterpret_cast<const short8_t*>(Pb + (size_t)(16 * w + cc) * ROWB + ks * 64 + g * 16);

    f32x4 oacc[8];
    __builtin_amdgcn_s_setprio(1);
    #pragma unroll
    for (int dt = 0; dt < 4; ++dt) {       // phase A: output dims 0..63
        oacc[dt] = (f32x4){0.f, 0.f, 0.f, 0.f};
        #pragma unroll
        for (int ks = 0; ks < 4; ++ks) {
            short8_t vb = *reinterpret_cast<const short8_t*>(Vt + (size_t)(16 * dt + cc) * ROWB + ks * 64 + g * 16);
            oacc[dt] = __builtin_amdgcn_mfma_f32_16x16x32_bf16(pa[ks], vb, oacc[dt], 0, 0, 0);
        }
    }
    __builtin_amdgcn_s_setprio(0);
    __syncthreads();   // phase-A reads of Vt done

    // ---- write V phase 1 to Vt ----------------------------------------------
    {
        const float* fa = reinterpret_cast<const float*>(va);
        const float* fb = reinterpret_cast<const float*>(vbr);
        #pragma unroll
        for (int i = 0; i < 16; ++i) {
            const int dl = db * 16 + i;
            *reinterpret_cast<unsigned int*>(Vt + (size_t)dl * ROWB + kp * 4) = pk2bf(fa[i], fb[i]);
        }
    }
    __syncthreads();

    __builtin_amdgcn_s_setprio(1);
    #pragma unroll
    for (int dt = 4; dt < 8; ++dt) {       // phase B: output dims 64..127
        oacc[dt] = (f32x4){0.f, 0.f, 0.f, 0.f};
        #pragma unroll
        for (int ks = 0; ks < 4; ++ks) {
            short8_t vb = *reinterpret_cast<const short8_t*>(Vt + (size_t)(16 * (dt - 4) + cc) * ROWB + ks * 64 + g * 16);
            oacc[dt] = __builtin_amdgcn_mfma_f32_16x16x32_bf16(pa[ks], vb, oacc[dt], 0, 0, 0);
        }
    }
    __builtin_amdgcn_s_setprio(0);

    // ---- scatter per-round outputs ------------------------------------------
    #pragma unroll
    for (int jr = 0; jr < 4; ++jr) {
        const int q = 16 * w + 4 * g + jr;
        const int t = tks[q];
        const size_t base = (((size_t)b * HH + h) * SS + t) * DD + cc;
        if (!obf16) {
            float* op = (float*)o_ws;
            #pragma unroll
            for (int dt = 0; dt < 8; ++dt) op[base + 16 * dt] = oacc[dt][jr];
        } else {
            unsigned short* op = (unsigned short*)o_ws;
            #pragma unroll
            for (int dt = 0; dt < 8; ++dt) op[base + 16 * dt] = f2bf(oacc[dt][jr]);
        }
    }
}

// ---------------- Kernel D: softmax-combine over hash rounds -----------------
__global__ __launch_bounds__(256) void combine_kernel(
    const float* __restrict__ logits_ws, const void* __restrict__ o_ws,
    float* __restrict__ outp, const int obf16)
{
    const int gid = blockIdx.x * 256 + threadIdx.x;
    const int row = gid >> 5;     // (b,t)
    const int seg = gid & 31;     // 4-float segment of D
    const int b = row >> 12;
    const int t = row & 4095;

    float l[8];
    float m = -3.0e38f;
    #pragma unroll
    for (int hh = 0; hh < 8; ++hh) {
        l[hh] = logits_ws[((size_t)b * HH + hh) * SS + t];
        m = fmaxf(m, l[hh]);
    }
    float ssum = 0.f;
    #pragma unroll
    for (int hh = 0; hh < 8; ++hh) { l[hh] = __expf(l[hh] - m); ssum += l[hh]; }
    const float inv = 1.0f / ssum;

    float a0 = 0.f, a1 = 0.f, a2 = 0.f, a3 = 0.f;
    #pragma unroll
    for (int hh = 0; hh < 8; ++hh) {
        const float wgt = l[hh] * inv;
        const size_t base = (((size_t)b * HH + hh) * SS + t) * DD + seg * 4;
        if (!obf16) {
            float4 ov = *reinterpret_cast<const float4*>((const float*)o_ws + base);
            a0 = fmaf(wgt, ov.x, a0); a1 = fmaf(wgt, ov.y, a1);
            a2 = fmaf(wgt, ov.z, a2); a3 = fmaf(wgt, ov.w, a3);
        } else {
            uint2 u = *reinterpret_cast<const uint2*>((const unsigned short*)o_ws + base);
            a0 = fmaf(wgt, bf2f((unsigned short)(u.x & 0xffffu)), a0);
            a1 = fmaf(wgt, bf2f((unsigned short)(u.x >> 16)), a1);
            a2 = fmaf(wgt, bf2f((unsigned short)(u.y & 0xffffu)), a2);
            a3 = fmaf(wgt, bf2f((unsigned short)(u.y >> 16)), a3);
        }
    }
    *reinterpret_cast<float4*>(outp + ((size_t)b * SS + t) * DD + seg * 4) =
        make_float4(a0, a1, a2, a3);
}

extern "C" void kernel_launch(void* const* d_in, const int* in_sizes, int n_in,
                              void* d_out, int out_size, void* d_ws, size_t ws_size,
                              hipStream_t stream) {
    const float* qk  = (const float*)d_in[0];
    const float* v   = (const float*)d_in[1];
    const float* rot = (const float*)d_in[2];

    float* out        = (float*)d_out;
    float* bucket_out = out + (size_t)BB * SS * DD;   // buckets written as f32

    char* ws = (char*)d_ws;
    int*            st        = (int*)ws;                              // 1,048,576 B
    unsigned char*  bucket_ws = (unsigned char*)(ws + 1048576);        //   262,144 B
    float*          logits_ws = (float*)(ws + 1048576 + 262144);       // 1,048,576 B
    void*           o_ws      = (void*)(ws + 2359296);                 // big scratch

    const int obf16 = 1;   // bf16 o-scratch: halves attn WRITE + combine read traffic

    hipLaunchKernelGGL(hash_kernel,    dim3(2048), dim3(256), 0, stream, qk, rot, bucket_ws, bucket_out);
    hipLaunchKernelGGL(sort_kernel,    dim3(64),   dim3(256), 0, stream, bucket_ws, st);
    hipLaunchKernelGGL(attn_kernel,    dim3(4096), dim3(256), 0, stream, qk, v, st, logits_ws, o_ws, obf16);
    hipLaunchKernelGGL(combine_kernel, dim3(4096), dim3(256), 0, stream, logits_ws, o_ws, out, obf16);
}

// Round 20
// 153.794 us; speedup vs baseline: 1.3409x; 1.0052x over previous
//
#include <hip/hip_runtime.h>
#include <hip/hip_bf16.h>

#define BB 8
#define SS 4096
#define DD 128
#define HH 8
#define NBUCK 64
#define CHUNKSZ 64
#define NCHUNK 512      // HH*SS/CHUNKSZ
#define HSTOT 32768     // HH*SS
#define ROWB 272        // bf16 tile row stride in bytes (128*2 + 16 pad)

typedef __attribute__((ext_vector_type(8))) short short8_t;   // 8 bf16 = 4 VGPR
typedef __attribute__((ext_vector_type(4))) float f32x4;

static __device__ __forceinline__ unsigned short f2bf(float f) {
    __hip_bfloat16 h = __float2bfloat16(f);
    return *reinterpret_cast<unsigned short*>(&h);
}
static __device__ __forceinline__ unsigned int pk2bf(float lo, float hi) {
    __hip_bfloat162 h = __float22bfloat162_rn(make_float2(lo, hi));   // v_cvt_pk_bf16_f32
    return *reinterpret_cast<unsigned int*>(&h);
}
static __device__ __forceinline__ float bf2f(unsigned short u) {
    return __uint_as_float(((unsigned int)u) << 16);
}

// ---------------- Kernel A: LSH hashing (register-resident) ------------------
// R9 structure + R12 XCD batch pinning + R19 rot-slice LDS staging (60->42us).
// R20: '#pragma unroll 4' on the c-loop -- widens the scheduler window so
// next-iteration q loads (L2, ~200cyc) hoist behind the current 128-FMA block.
// FMA order per (token,j) unchanged (c ascending, ff ascending) -> bit-exact.
__global__ __launch_bounds__(256) void hash_kernel(
    const float* __restrict__ qk, const float* __restrict__ rot,
    unsigned char* __restrict__ bucket_ws, float* __restrict__ bucket_out)
{
    __shared__ float rots[128 * 32];
    const int tid = threadIdx.x;
    const int bid = blockIdx.x;            // 0..2047 = tile(5) | h(3) | b(3)
    const int b   = bid & 7;               // XCD-pinned batch
    const int h   = (bid >> 3) & 7;
    const int t0  = (bid >> 6) * 128;
    const int tg  = tid >> 3;              // token group 0..31 (4 tokens each)
    const int jq  = tid & 7;               // j-quad 0..7 (4 columns each)

    // ---- stage rot[f][h*32 .. h*32+31] -> rots[f][0..31] (16KB, once) -------
    {
        const int row = tid >> 1, half16 = tid & 1;   // 128 rows x 2 halves
        const float* src = rot + (size_t)row * 256 + h * 32 + half16 * 16;
        float* dst = &rots[row * 32 + half16 * 16];
        #pragma unroll
        for (int i = 0; i < 4; ++i)
            *reinterpret_cast<float4*>(dst + i * 4) =
                *reinterpret_cast<const float4*>(src + i * 4);
    }
    __syncthreads();

    const float* qbase = qk + ((size_t)b * SS + t0 + tg * 4) * DD;

    float acc[4][4];
    #pragma unroll
    for (int r = 0; r < 4; ++r)
        #pragma unroll
        for (int j = 0; j < 4; ++j) acc[r][j] = 0.f;

    #pragma unroll 4
    for (int c = 0; c < 16; ++c) {         // f in chunks of 8
        float4 qv[4][2];
        #pragma unroll
        for (int r = 0; r < 4; ++r) {
            qv[r][0] = *reinterpret_cast<const float4*>(qbase + r * DD + c * 8);
            qv[r][1] = *reinterpret_cast<const float4*>(qbase + r * DD + c * 8 + 4);
        }
        float4 rv[8];
        #pragma unroll
        for (int ff = 0; ff < 8; ++ff)
            rv[ff] = *reinterpret_cast<const float4*>(&rots[(c * 8 + ff) * 32 + jq * 4]);
        #pragma unroll
        for (int ff = 0; ff < 8; ++ff) {
            #pragma unroll
            for (int r = 0; r < 4; ++r) {
                const float4 qh = qv[r][ff >> 2];
                const float qs = (ff & 2) ? ((ff & 1) ? qh.w : qh.z)
                                          : ((ff & 1) ? qh.y : qh.x);
                acc[r][0] = fmaf(qs, rv[ff].x, acc[r][0]);
                acc[r][1] = fmaf(qs, rv[ff].y, acc[r][1]);
                acc[r][2] = fmaf(qs, rv[ff].z, acc[r][2]);
                acc[r][3] = fmaf(qs, rv[ff].w, acc[r][3]);
            }
        }
    }

    const float TAU = 0.01f;
    #pragma unroll
    for (int r = 0; r < 4; ++r) {
        float bv = -3.0e38f; int bi = 0;
        #pragma unroll
        for (int j = 0; j < 4; ++j) {
            float v = acc[r][j];
            if (v > bv) { bv = v; bi = jq * 4 + j; }
        }
        #pragma unroll
        for (int j = 0; j < 4; ++j) {
            float v = -acc[r][j];
            if (v > bv) { bv = v; bi = 32 + jq * 4 + j; }
        }
        #pragma unroll
        for (int off = 1; off < 8; off <<= 1) {
            float ov = __shfl_xor(bv, off);
            int   oi = __shfl_xor(bi, off);
            if (ov > bv || (ov == bv && oi < bi)) { bv = ov; bi = oi; }
        }
        const float thrv = bv - TAU;
        int cnt = 0;
        #pragma unroll
        for (int j = 0; j < 4; ++j) {
            cnt += (acc[r][j]  > thrv) ? 1 : 0;
            cnt += (-acc[r][j] > thrv) ? 1 : 0;
        }
        #pragma unroll
        for (int off = 1; off < 8; off <<= 1) cnt += __shfl_xor(cnt, off);

        const int t = t0 + tg * 4 + r;
        if (cnt > 1) {
            const float* qrow = qk + ((size_t)b * SS + t) * DD;
            double bvd = -1.0e300; int bid2 = 64;
            #pragma unroll
            for (int j = 0; j < 4; ++j) {
                const bool fp = (acc[r][j] > thrv);
                const bool fn = (-acc[r][j] > thrv);
                if (fp || fn) {
                    const float* rcol = rot + h * 32 + jq * 4 + j;
                    double a = 0.0;
                    for (int f = 0; f < DD; ++f)
                        a = fma((double)qrow[f], (double)rcol[(size_t)f * (HH * 32)], a);
                    if (fp &&  a > bvd)                         { bvd = a;  bid2 = jq * 4 + j; }
                    if (fn && (-a > bvd ||
                               (-a == bvd && 32 + jq * 4 + j < bid2))) { bvd = -a; bid2 = 32 + jq * 4 + j; }
                }
            }
            #pragma unroll
            for (int off = 1; off < 8; off <<= 1) {
                double ov = __shfl_xor(bvd, off);
                int    oi = __shfl_xor(bid2, off);
                if (ov > bvd || (ov == bvd && oi < bid2)) { bvd = ov; bid2 = oi; }
            }
            bi = bid2;
        }
        if (jq == 0) {
            const size_t o = ((size_t)b * HH + h) * SS + t;
            bucket_ws[o]  = (unsigned char)bi;
            bucket_out[o] = (float)(bi + h * NBUCK);
        }
    }
}

// ---------------- Kernel B: stable counting sort per (b,h) -------------------
__global__ __launch_bounds__(256) void sort_kernel(
    const unsigned char* __restrict__ bucket_ws, int* __restrict__ st)
{
    __shared__ unsigned int hist[256 * 65];   // padded stride 65
    __shared__ unsigned int totals[64];
    const int tid = threadIdx.x;
    const int bh  = blockIdx.x;               // 0..63 = b*8+h

    unsigned int* hrow = &hist[tid * 65];
    #pragma unroll
    for (int j = 0; j < 65; ++j) hrow[j] = 0u;

    const uint4 raw = *reinterpret_cast<const uint4*>(bucket_ws + (size_t)bh * SS + tid * 16);
    unsigned int w[4] = {raw.x, raw.y, raw.z, raw.w};

    #pragma unroll
    for (int c = 0; c < 16; ++c) {
        unsigned int bk = (w[c >> 2] >> ((c & 3) * 8)) & 255u;
        hrow[bk] += 1u;
    }
    __syncthreads();

    if (tid < 64) {
        unsigned int run = 0;
        for (int c2 = 0; c2 < 256; ++c2) {
            unsigned int x = hist[c2 * 65 + tid];
            hist[c2 * 65 + tid] = run;
            run += x;
        }
        totals[tid] = run;
    }
    __syncthreads();
    if (tid == 0) {
        unsigned int base = 0;
        for (int k = 0; k < 64; ++k) { unsigned int x = totals[k]; totals[k] = base; base += x; }
    }
    __syncthreads();

    int* dst = st + (size_t)bh * SS;
    #pragma unroll
    for (int c = 0; c < 16; ++c) {
        unsigned int bk = (w[c >> 2] >> ((c & 3) * 8)) & 255u;
        unsigned int pos = totals[bk] + hrow[bk];
        hrow[bk] += 1u;
        dst[pos] = tid * 16 + c;
    }
}

// ---------------- Kernel C: chunked attention via bf16 MFMA ------------------
// R12 structure: LDS -> 4 blocks/CU, XCD batch pinning, setprio (T5),
// V in two 64-dim phases with early prefetch (T14), fast exp/log (R15),
// ninv via lane-pair shfl during K-stage (R16; 5 barriers). Measured ~93us,
// latency-bound (MfmaUtil 7 / VALU 29 / Occ 39) -- five structural attempts
// all neutral; do not churn.
__global__ __launch_bounds__(256, 4) void attn_kernel(
    const float* __restrict__ qk, const float* __restrict__ vv,
    const int* __restrict__ st, float* __restrict__ logits_ws,
    void* __restrict__ o_ws, const int obf16)
{
    __shared__ __align__(16) char smem[35840];
    char*  Kb    = smem;
    char*  Pb    = smem;                       // after Kb retired
    char*  Vt    = smem + 17408;               // 64 dim-rows x 272 B
    int*   tks   = (int*)(smem + 34816);
    float* ninv  = (float*)(smem + 35328);

    const int tid = threadIdx.x;
    const int bc  = blockIdx.x;
    const int b   = bc & 7;                    // XCD-pinned batch
    const int c   = bc >> 3;                   // chunk 0..511
    const int h   = c >> 6;
    const int cprev = (c == 0) ? (NCHUNK - 1) : (c - 1);
    const int* stb  = st + (size_t)b * HSTOT;

    // ---- V phase-0 prefetch: issue FIRST (T14) ------------------------------
    const int kp = tid & 63;                   // token pair 2kp, 2kp+1
    const int db = tid >> 6;                   // dim sub-block (16 dims)
    const int idxa = 2 * kp, idxb = 2 * kp + 1;
    const int tva = stb[(size_t)((idxa < 64) ? c : cprev) * CHUNKSZ + (idxa & 63)];
    const int tvb = stb[(size_t)((idxb < 64) ? c : cprev) * CHUNKSZ + (idxb & 63)];
    const float* vra = vv + ((size_t)b * SS + tva) * DD + db * 16;
    const float* vrb = vv + ((size_t)b * SS + tvb) * DD + db * 16;
    float4 va[4], vbr[4];
    #pragma unroll
    for (int i = 0; i < 4; ++i) {
        va[i]  = *reinterpret_cast<const float4*>(vra + i * 4);
        vbr[i] = *reinterpret_cast<const float4*>(vrb + i * 4);
    }

    // own K-row index straight from global (L2-hot) -- off the barrier path
    const int rowk  = tid >> 1, halfk = tid & 1;
    const int t_mine = stb[(size_t)((rowk < 64) ? c : cprev) * CHUNKSZ + (rowk & 63)];

    if (tid < 128) {                           // LDS copy for later phases
        tks[tid] = stb[(size_t)((tid < 64) ? c : cprev) * CHUNKSZ + (tid & 63)];
    }

    // ---- stage K (raw qk rows, bf16) + ninv via lane-pair shfl --------------
    {
        const float* srow = qk + ((size_t)b * SS + t_mine) * DD + halfk * 64;
        char* krow = Kb + (size_t)rowk * ROWB + halfk * 128;
        float ss = 0.f;
        #pragma unroll
        for (int i = 0; i < 8; ++i) {
            float4 v0 = *reinterpret_cast<const float4*>(srow + i * 8);
            float4 v1 = *reinterpret_cast<const float4*>(srow + i * 8 + 4);
            ss = fmaf(v0.x, v0.x, ss); ss = fmaf(v0.y, v0.y, ss);
            ss = fmaf(v0.z, v0.z, ss); ss = fmaf(v0.w, v0.w, ss);
            ss = fmaf(v1.x, v1.x, ss); ss = fmaf(v1.y, v1.y, ss);
            ss = fmaf(v1.z, v1.z, ss); ss = fmaf(v1.w, v1.w, ss);
            uint4 pk;
            pk.x = pk2bf(v0.x, v0.y); pk.y = pk2bf(v0.z, v0.w);
            pk.z = pk2bf(v1.x, v1.y); pk.w = pk2bf(v1.z, v1.w);
            *reinterpret_cast<uint4*>(krow + i * 16) = pk;
        }
        // halves of row rowk are in adjacent lanes 2*rowk, 2*rowk+1
        const float other = __shfl_xor(ss, 1);
        if (halfk == 0)    // (half0)+(half1): same order as old psums[2t]+psums[2t+1]
            ninv[rowk] = rsqrtf(ss + other + 1e-6f) * 0.088388347648318447f;
    }
    __syncthreads();   // single barrier: K tile + ninv + tks all visible

    const int w  = tid >> 6;     // wave id: q-tile rows 16w..16w+15
    const int ln = tid & 63;
    const int cc = ln & 15;      // fragment col lane
    const int g  = ln >> 4;      // fragment k-group / row-group

    // ---- QK^T ---------------------------------------------------------------
    short8_t aq[4];
    #pragma unroll
    for (int ks = 0; ks < 4; ++ks)
        aq[ks] = *reinterpret_cast<const short8_t*>(Kb + (size_t)(16 * w + cc) * ROWB + ks * 64 + g * 16);

    f32x4 acc[8];
    __builtin_amdgcn_s_setprio(1);
    #pragma unroll
    for (int j = 0; j < 8; ++j) {
        acc[j] = (f32x4){0.f, 0.f, 0.f, 0.f};
        #pragma unroll
        for (int ks = 0; ks < 4; ++ks) {
            short8_t bk = *reinterpret_cast<const short8_t*>(Kb + (size_t)(16 * j + cc) * ROWB + ks * 64 + g * 16);
            acc[j] = __builtin_amdgcn_mfma_f32_16x16x32_bf16(aq[ks], bk, acc[j], 0, 0, 0);
        }
    }
    __builtin_amdgcn_s_setprio(0);

    // ---- softmax (regs, fast-math exp/log) ----------------------------------
    float lse[4];
    float pr[8][4];
    #pragma unroll
    for (int jr = 0; jr < 4; ++jr) {
        const int q  = 16 * w + 4 * g + jr;
        const int tq = tks[q];
        float m = -3.0e38f;
        #pragma unroll
        for (int j = 0; j < 8; ++j) {
            const int k = 16 * j + cc;
            float val = acc[j][jr] * ninv[k];
            if (tks[k] == tq) val = -1e5f;
            pr[j][jr] = val;
            m = fmaxf(m, val);
        }
        #pragma unroll
        for (int off = 1; off < 16; off <<= 1) m = fmaxf(m, __shfl_xor(m, off));
        float ssum = 0.f;
        #pragma unroll
        for (int j = 0; j < 8; ++j) { float ex = __expf(pr[j][jr] - m); pr[j][jr] = ex; ssum += ex; }
        #pragma unroll
        for (int off = 1; off < 16; off <<= 1) ssum += __shfl_xor(ssum, off);
        const float inv = 1.0f / ssum;
        #pragma unroll
        for (int j = 0; j < 8; ++j) pr[j][jr] *= inv;
        lse[jr] = m + __logf(ssum);
    }

    __syncthreads();   // all waves done reading Kb; Pb/Vt may be written

    // ---- write P (bf16) -----------------------------------------------------
    #pragma unroll
    for (int jr = 0; jr < 4; ++jr) {
        const int q = 16 * w + 4 * g + jr;
        #pragma unroll
        for (int j = 0; j < 8; ++j)
            *reinterpret_cast<unsigned short*>(Pb + (size_t)q * ROWB + (16 * j + cc) * 2) = f2bf(pr[j][jr]);
    }
    if (cc == 0) {
        #pragma unroll
        for (int jr = 0; jr < 4; ++jr) {
            const int q = 16 * w + 4 * g + jr;
            logits_ws[((size_t)b * HH + h) * SS + tks[q]] = lse[jr];
        }
    }
    // ---- write V phase 0 to Vt ----------------------------------------------
    {
        const float* fa = reinterpret_cast<const float*>(va);
        const float* fb = reinterpret_cast<const float*>(vbr);
        #pragma unroll
        for (int i = 0; i < 16; ++i) {
            const int dl = db * 16 + i;
            *reinterpret_cast<unsigned int*>(Vt + (size_t)dl * ROWB + kp * 4) = pk2bf(fa[i], fb[i]);
        }
    }
    // ---- prefetch V phase 1 (dims 64..127) into regs (T14 split) ------------
    #pragma unroll
    for (int i = 0; i < 4; ++i) {
        va[i]  = *reinterpret_cast<const float4*>(vra + 64 + i * 4);
        vbr[i] = *reinterpret_cast<const float4*>(vrb + 64 + i * 4);
    }
    __syncthreads();   // Pb + Vt(phase 0) visible

    // ---- PV -----------------------------------------------------------------
    short8_t pa[4];
    #pragma unroll
    for (int ks = 0; ks < 4; ++ks)
        pa[ks] = *reinterpret_cast<const short8_t*>(Pb + (size_t)(16 * w + cc) * ROWB + ks * 64 + g * 16);

    f32x4 oacc[8];
    __builtin_amdgcn_s_setprio(1);
    #pragma unroll
    for (int dt = 0; dt < 4; ++dt) {       // phase A: output dims 0..63
        oacc[dt] = (f32x4){0.f, 0.f, 0.f, 0.f};
        #pragma unroll
        for (int ks = 0; ks < 4; ++ks) {
            short8_t vb = *reinterpret_cast<const short8_t*>(Vt + (size_t)(16 * dt + cc) * ROWB + ks * 64 + g * 16);
            oacc[dt] = __builtin_amdgcn_mfma_f32_16x16x32_bf16(pa[ks], vb, oacc[dt], 0, 0, 0);
        }
    }
    __builtin_amdgcn_s_setprio(0);
    __syncthreads();   // phase-A reads of Vt done

    // ---- write V phase 1 to Vt ----------------------------------------------
    {
        const float* fa = reinterpret_cast<const float*>(va);
        const float* fb = reinterpret_cast<const float*>(vbr);
        #pragma unroll
        for (int i = 0; i < 16; ++i) {
            const int dl = db * 16 + i;
            *reinterpret_cast<unsigned int*>(Vt + (size_t)dl * ROWB + kp * 4) = pk2bf(fa[i], fb[i]);
        }
    }
    __syncthreads();

    __builtin_amdgcn_s_setprio(1);
    #pragma unroll
    for (int dt = 4; dt < 8; ++dt) {       // phase B: output dims 64..127
        oacc[dt] = (f32x4){0.f, 0.f, 0.f, 0.f};
        #pragma unroll
        for (int ks = 0; ks < 4; ++ks) {
            short8_t vb = *reinterpret_cast<const short8_t*>(Vt + (size_t)(16 * (dt - 4) + cc) * ROWB + ks * 64 + g * 16);
            oacc[dt] = __builtin_amdgcn_mfma_f32_16x16x32_bf16(pa[ks], vb, oacc[dt], 0, 0, 0);
        }
    }
    __builtin_amdgcn_s_setprio(0);

    // ---- scatter per-round outputs ------------------------------------------
    #pragma unroll
    for (int jr = 0; jr < 4; ++jr) {
        const int q = 16 * w + 4 * g + jr;
        const int t = tks[q];
        const size_t base = (((size_t)b * HH + h) * SS + t) * DD + cc;
        if (!obf16) {
            float* op = (float*)o_ws;
            #pragma unroll
            for (int dt = 0; dt < 8; ++dt) op[base + 16 * dt] = oacc[dt][jr];
        } else {
            unsigned short* op = (unsigned short*)o_ws;
            #pragma unroll
            for (int dt = 0; dt < 8; ++dt) op[base + 16 * dt] = f2bf(oacc[dt][jr]);
        }
    }
}

// ---------------- Kernel D: softmax-combine over hash rounds -----------------
__global__ __launch_bounds__(256) void combine_kernel(
    const float* __restrict__ logits_ws, const void* __restrict__ o_ws,
    float* __restrict__ outp, const int obf16)
{
    const int gid = blockIdx.x * 256 + threadIdx.x;
    const int row = gid >> 5;     // (b,t)
    const int seg = gid & 31;     // 4-float segment of D
    const int b = row >> 12;
    const int t = row & 4095;

    float l[8];
    float m = -3.0e38f;
    #pragma unroll
    for (int hh = 0; hh < 8; ++hh) {
        l[hh] = logits_ws[((size_t)b * HH + hh) * SS + t];
        m = fmaxf(m, l[hh]);
    }
    float ssum = 0.f;
    #pragma unroll
    for (int hh = 0; hh < 8; ++hh) { l[hh] = __expf(l[hh] - m); ssum += l[hh]; }
    const float inv = 1.0f / ssum;

    float a0 = 0.f, a1 = 0.f, a2 = 0.f, a3 = 0.f;
    #pragma unroll
    for (int hh = 0; hh < 8; ++hh) {
        const float wgt = l[hh] * inv;
        const size_t base = (((size_t)b * HH + hh) * SS + t) * DD + seg * 4;
        if (!obf16) {
            float4 ov = *reinterpret_cast<const float4*>((const float*)o_ws + base);
            a0 = fmaf(wgt, ov.x, a0); a1 = fmaf(wgt, ov.y, a1);
            a2 = fmaf(wgt, ov.z, a2); a3 = fmaf(wgt, ov.w, a3);
        } else {
            uint2 u = *reinterpret_cast<const uint2*>((const unsigned short*)o_ws + base);
            a0 = fmaf(wgt, bf2f((unsigned short)(u.x & 0xffffu)), a0);
            a1 = fmaf(wgt, bf2f((unsigned short)(u.x >> 16)), a1);
            a2 = fmaf(wgt, bf2f((unsigned short)(u.y & 0xffffu)), a2);
            a3 = fmaf(wgt, bf2f((unsigned short)(u.y >> 16)), a3);
        }
    }
    *reinterpret_cast<float4*>(outp + ((size_t)b * SS + t) * DD + seg * 4) =
        make_float4(a0, a1, a2, a3);
}

extern "C" void kernel_launch(void* const* d_in, const int* in_sizes, int n_in,
                              void* d_out, int out_size, void* d_ws, size_t ws_size,
                              hipStream_t stream) {
    const float* qk  = (const float*)d_in[0];
    const float* v   = (const float*)d_in[1];
    const float* rot = (const float*)d_in[2];

    float* out        = (float*)d_out;
    float* bucket_out = out + (size_t)BB * SS * DD;   // buckets written as f32

    char* ws = (char*)d_ws;
    int*            st        = (int*)ws;                              // 1,048,576 B
    unsigned char*  bucket_ws = (unsigned char*)(ws + 1048576);        //   262,144 B
    float*          logits_ws = (float*)(ws + 1048576 + 262144);       // 1,048,576 B
    void*           o_ws      = (void*)(ws + 2359296);                 // big scratch

    const int obf16 = 1;   // bf16 o-scratch: halves attn WRITE + combine read traffic

    hipLaunchKernelGGL(hash_kernel,    dim3(2048), dim3(256), 0, stream, qk, rot, bucket_ws, bucket_out);
    hipLaunchKernelGGL(sort_kernel,    dim3(64),   dim3(256), 0, stream, bucket_ws, st);
    hipLaunchKernelGGL(attn_kernel,    dim3(4096), dim3(256), 0, stream, qk, v, st, logits_ws, o_ws, obf16);
    hipLaunchKernelGGL(combine_kernel, dim3(4096), dim3(256), 0, stream, logits_ws, o_ws, out, obf16);
}